// Round 2
// baseline (4118.900 us; speedup 1.0000x reference)
//
#include <hip/hip_runtime.h>
#include <math.h>

// Problem constants (B=8, H=W=128, C=512, HEADS=8 -> kt=64 via _k_tokens)
#define NB     8
#define NSEQ   16384
#define NTOK   (NB*NSEQ)      // 131072
#define CH     512
#define CRD    256
#define NHEAD  8
#define DH     64
#define DHQ    32
#define KT     64
#define HH     128
#define WW     128
#define SCALEQ 0.17677669529663687f   // (64*0.5)^-0.5

// ---------------- wave helpers (wave = 64 lanes) ----------------
__device__ __forceinline__ float wsum(float v){
#pragma unroll
  for (int o=32;o;o>>=1) v += __shfl_xor(v,o,64);
  return v;
}
__device__ __forceinline__ float wmax(float v){
#pragma unroll
  for (int o=32;o;o>>=1) v = fmaxf(v,__shfl_xor(v,o,64));
  return v;
}

// ---------------- taps: T9[token][j] = sum_c x[token,c]*curv_w[c,j] ----------------
__global__ __launch_bounds__(256) void taps_kernel(const float* __restrict__ x,
    const float* __restrict__ curv_w, float* __restrict__ T9)
{
  __shared__ float ws_[CH*9];   // 18 KB
  int tid = threadIdx.x;
  for (int i=tid;i<CH*9;i+=256) ws_[i] = curv_w[i];
  __syncthreads();
  int wid = tid>>6, lane = tid&63;
  size_t token = (size_t)blockIdx.x*4 + wid;
  float acc[9] = {0,0,0,0,0,0,0,0,0};
#pragma unroll
  for (int i=0;i<8;++i){
    int c = lane + i*64;                    // stride-1 lanes: LDS addr 9c+j, gcd(9,32)=1 -> 2-way max (free)
    float xk = x[token*CH + c];
    const float* wp = &ws_[c*9];
#pragma unroll
    for (int j=0;j<9;++j) acc[j] += xk*wp[j];
  }
#pragma unroll
  for (int j=0;j<9;++j) acc[j] = wsum(acc[j]);
  if (lane==0){
#pragma unroll
    for (int j=0;j<9;++j) T9[token*9+j] = acc[j];
  }
}

// ---------------- generic fp32 GEMM: C[M,N] = A[M,K] @ B[N,K]^T (+bias) ----------------
// 128x128x16 tile, 8x8 per thread, global->register prefetch double buffer.
#define GBM 128
#define GBN 128
#define GBK 16
__global__ __launch_bounds__(256) void gemm_abt(
    const float* __restrict__ A, const float* __restrict__ Bm,
    const float* __restrict__ bias, float* __restrict__ C,
    int M, int N, int K)
{
  __shared__ float As[GBK][GBM+4];
  __shared__ float Bs[GBK][GBN+4];
  const int tid = threadIdx.x;
  const int bm = blockIdx.x * GBM;
  const int bn = blockIdx.y * GBN;
  const int tx = tid & 15;     // col group (split-quad: cols tx*4 and 64+tx*4)
  const int ty = tid >> 4;     // row group
  const int lr = tid >> 2;     // load row 0..63
  const int lf = tid & 3;      // float4 slot in 16-wide k

  const float* Ap0 = A  + (size_t)(bm+lr)*K    + lf*4;
  const float* Ap1 = A  + (size_t)(bm+lr+64)*K + lf*4;
  const float* Bp0 = Bm + (size_t)(bn+lr)*K    + lf*4;
  const float* Bp1 = Bm + (size_t)(bn+lr+64)*K + lf*4;

  float acc[8][8];
#pragma unroll
  for (int i=0;i<8;++i)
#pragma unroll
    for (int j=0;j<8;++j) acc[i][j]=0.f;

  // prologue: prefetch K-tile 0 into registers
  float4 ra0 = *(const float4*)(Ap0);
  float4 ra1 = *(const float4*)(Ap1);
  float4 rb0 = *(const float4*)(Bp0);
  float4 rb1 = *(const float4*)(Bp1);

  for (int k0=0;k0<K;k0+=GBK){
    __syncthreads();   // previous compute done reading LDS (no-op cost on iter 0)
    As[lf*4+0][lr]=ra0.x; As[lf*4+1][lr]=ra0.y; As[lf*4+2][lr]=ra0.z; As[lf*4+3][lr]=ra0.w;
    As[lf*4+0][lr+64]=ra1.x; As[lf*4+1][lr+64]=ra1.y; As[lf*4+2][lr+64]=ra1.z; As[lf*4+3][lr+64]=ra1.w;
    Bs[lf*4+0][lr]=rb0.x; Bs[lf*4+1][lr]=rb0.y; Bs[lf*4+2][lr]=rb0.z; Bs[lf*4+3][lr]=rb0.w;
    Bs[lf*4+0][lr+64]=rb1.x; Bs[lf*4+1][lr+64]=rb1.y; Bs[lf*4+2][lr+64]=rb1.z; Bs[lf*4+3][lr+64]=rb1.w;
    __syncthreads();   // LDS tile ready
    if (k0+GBK < K){   // issue next tile's global loads; latency hides under compute
      ra0 = *(const float4*)(Ap0 + k0+GBK);
      ra1 = *(const float4*)(Ap1 + k0+GBK);
      rb0 = *(const float4*)(Bp0 + k0+GBK);
      rb1 = *(const float4*)(Bp1 + k0+GBK);
    }
#pragma unroll
    for (int kk=0;kk<GBK;++kk){
      float a[8], b[8];
      *(float4*)&a[0] = *(const float4*)&As[kk][ty*4];
      *(float4*)&a[4] = *(const float4*)&As[kk][64+ty*4];
      *(float4*)&b[0] = *(const float4*)&Bs[kk][tx*4];
      *(float4*)&b[4] = *(const float4*)&Bs[kk][64+tx*4];
#pragma unroll
      for (int i=0;i<8;++i)
#pragma unroll
        for (int j=0;j<8;++j) acc[i][j] = fmaf(a[i], b[j], acc[i][j]);
    }
  }
#pragma unroll
  for (int i=0;i<8;++i){
    int row = bm + (i<4 ? ty*4+i : 64+ty*4+(i-4));
#pragma unroll
    for (int jg=0;jg<2;++jg){
      int col = bn + (jg==0 ? tx*4 : 64+tx*4);
      float b0=0.f,b1=0.f,b2v=0.f,b3=0.f;
      if (bias){ b0=bias[col]; b1=bias[col+1]; b2v=bias[col+2]; b3=bias[col+3]; }
      float4 o;
      o.x = acc[i][jg*4+0]+b0;
      o.y = acc[i][jg*4+1]+b1;
      o.z = acc[i][jg*4+2]+b2v;
      o.w = acc[i][jg*4+3]+b3;
      *(float4*)(C + (size_t)row*N + col) = o;
    }
  }
}

// ---------------- 9-tap spatial combine -> curv_raw (pre-LN) ----------------
__global__ __launch_bounds__(256) void curv_combine(const float* __restrict__ T9,
    float* __restrict__ curv_raw)
{
  int gid = blockIdx.x*256 + threadIdx.x;
  int b = gid >> 14;
  int p = gid & (NSEQ-1);
  int i = p >> 7;
  int k = p & (WW-1);
  float s = 0.f;
#pragma unroll
  for (int dy=-1;dy<=1;++dy){
    int ii = i+dy;
    if (ii<0||ii>=HH) continue;
#pragma unroll
    for (int dx=-1;dx<=1;++dx){
      int kk = k+dx;
      if (kk<0||kk>=WW) continue;
      int j = (dy+1)*3 + (dx+1);
      s += T9[((size_t)b*NSEQ + ii*WW + kk)*9 + j];
    }
  }
  curv_raw[gid] = s * (1.0f/512.0f);
}

// ---------------- per-batch LN stats over N=16384 ----------------
__global__ __launch_bounds__(256) void stats_kernel(const float* __restrict__ curv_raw,
    float* __restrict__ stats)
{
  __shared__ float red[256];
  int b = blockIdx.x, tid = threadIdx.x;
  const float* cr = curv_raw + (size_t)b*NSEQ;
  float s=0.f;
  for (int i=tid;i<NSEQ;i+=256) s += cr[i];
  red[tid]=s; __syncthreads();
  for (int st=128;st;st>>=1){ if(tid<st) red[tid]+=red[tid+st]; __syncthreads(); }
  float mean = red[0] * (1.0f/NSEQ);
  __syncthreads();
  float vs=0.f;
  for (int i=tid;i<NSEQ;i+=256){ float d=cr[i]-mean; vs += d*d; }
  red[tid]=vs; __syncthreads();
  for (int st=128;st;st>>=1){ if(tid<st) red[tid]+=red[tid+st]; __syncthreads(); }
  if (tid==0){ stats[2*b]=mean; stats[2*b+1]=rsqrtf(red[0]*(1.0f/NSEQ) + 1e-5f); }
}

// ---------------- gate layer-2 + sigmoid + normalized curv + score ----------------
__global__ __launch_bounds__(256) void score_kernel(const float* __restrict__ h_pre,
    const float* __restrict__ w2, const float* __restrict__ b2,
    const float* __restrict__ curv_raw, const float* __restrict__ stats,
    float* __restrict__ score, float* __restrict__ curv_norm)
{
  int tid=threadIdx.x; int wid=tid>>6, lane=tid&63;
  size_t token = (size_t)blockIdx.x*4 + wid;
  int b = (int)(token >> 14);
  const float* h = h_pre + token*CRD;
  float acc=0.f;
#pragma unroll
  for (int i=0;i<4;++i){
    int c = lane + i*64;
    float hv = fmaxf(h[c], 0.f);   // relu applied here (h_pre stored pre-activation)
    acc += hv * w2[c];
  }
  acc = wsum(acc);
  if (lane==0){
    float z = acc + b2[0];
    float gate = 1.0f/(1.0f + expf(-z));
    float cn = (curv_raw[token] - stats[2*b]) * stats[2*b+1];
    curv_norm[token] = cn;
    score[token] = 0.5f*(fabsf(cn) + gate);
  }
}

// ---------------- exact jax.lax.top_k(64): descending, ties -> lowest index ----------------
__global__ __launch_bounds__(256) void topk_kernel(const float* __restrict__ score,
    int* __restrict__ idx_out, float* __restrict__ val_out)
{
  __shared__ unsigned char flag[NSEQ];  // 16 KB
  __shared__ float wv[4]; __shared__ int wi[4];
  int b = blockIdx.x, tid = threadIdx.x;
  const float* sc = score + (size_t)b*NSEQ;
  for (int i=tid;i<NSEQ;i+=256) flag[i]=0;
  __syncthreads();
  int wid=tid>>6, lane=tid&63;
  for (int r=0;r<KT;++r){
    float best=-1e30f; int bi=1<<30;
    for (int i=tid;i<NSEQ;i+=256){
      if (flag[i]) continue;
      float v = sc[i];
      if (v>best || (v==best && i<bi)){ best=v; bi=i; }
    }
#pragma unroll
    for (int o=32;o;o>>=1){
      float ov=__shfl_xor(best,o,64); int oi=__shfl_xor(bi,o,64);
      if (ov>best || (ov==best && oi<bi)){ best=ov; bi=oi; }
    }
    if (lane==0){ wv[wid]=best; wi[wid]=bi; }
    __syncthreads();
    if (tid==0){
      float fb=wv[0]; int fi=wi[0];
      for (int w=1;w<4;++w){
        if (wv[w]>fb || (wv[w]==fb && wi[w]<fi)){ fb=wv[w]; fi=wi[w]; }
      }
      idx_out[b*KT+r]=fi; val_out[b*KT+r]=fb; flag[fi]=1;
    }
    __syncthreads();
  }
}

// ---------------- kv = gelu(LN(x_topk @ kvr_w^T + kvr_b)); also gather curv_topk ----------------
__global__ __launch_bounds__(256) void kva_kernel(const float* __restrict__ x,
    const int* __restrict__ topk_idx, const float* __restrict__ kvr_w,
    const float* __restrict__ kvr_b, const float* __restrict__ ln_g,
    const float* __restrict__ ln_b, const float* __restrict__ curv_norm,
    float* __restrict__ kv, float* __restrict__ curv_top)
{
  __shared__ float xs[CH];
  __shared__ float red[CRD];
  int blk=blockIdx.x; int b=blk>>6, t=blk&63; int tid=threadIdx.x;
  int row = topk_idx[b*KT+t];
  const float* xr = x + ((size_t)b*NSEQ + row)*CH;
  xs[tid]=xr[tid]; xs[tid+256]=xr[tid+256];
  __syncthreads();
  float acc = kvr_b[tid];
  const float4* wr = (const float4*)(kvr_w + (size_t)tid*CH);
  const float4* x4 = (const float4*)xs;
#pragma unroll 8
  for (int i=0;i<CH/4;++i){
    float4 w4=wr[i]; float4 xv=x4[i];
    acc += w4.x*xv.x + w4.y*xv.y + w4.z*xv.z + w4.w*xv.w;
  }
  red[tid]=acc; __syncthreads();
  for (int st=128;st;st>>=1){ if(tid<st) red[tid]+=red[tid+st]; __syncthreads(); }
  float mean = red[0]*(1.0f/CRD);
  __syncthreads();
  float d = acc-mean;
  red[tid]=d*d; __syncthreads();
  for (int st=128;st;st>>=1){ if(tid<st) red[tid]+=red[tid+st]; __syncthreads(); }
  float rstd = rsqrtf(red[0]*(1.0f/CRD) + 1e-5f);
  float y = (acc-mean)*rstd*ln_g[tid] + ln_b[tid];
  float ge = 0.5f*y*(1.0f + erff(y*0.70710678118654752f));   // exact gelu
  kv[((size_t)b*KT+t)*CRD + tid] = ge;
  if (tid==0) curv_top[b*KT+t] = curv_norm[(size_t)b*NSEQ + row];
}

// ---------------- kmat = kv@k_w^T ; v = (kv@v_w^T) * score_topk ----------------
__global__ __launch_bounds__(256) void kvb_kernel(const float* __restrict__ kv,
    const float* __restrict__ k_w, const float* __restrict__ v_w,
    const float* __restrict__ topk_val, float* __restrict__ kmat,
    float* __restrict__ vbuf)
{
  __shared__ float ks[CRD];
  int blk=blockIdx.x; int b=blk>>6, t=blk&63; int tid=threadIdx.x;
  ks[tid] = kv[((size_t)b*KT+t)*CRD + tid];
  __syncthreads();
  float sv = topk_val[b*KT+t];
  const float4* k4 = (const float4*)ks;
  const float4* wk = (const float4*)(k_w + (size_t)tid*CRD);
  float a=0.f;
#pragma unroll 8
  for (int i=0;i<CRD/4;++i){ float4 w4=wk[i]; float4 xv=k4[i]; a += w4.x*xv.x+w4.y*xv.y+w4.z*xv.z+w4.w*xv.w; }
  kmat[((size_t)b*KT+t)*CRD + tid] = a;
  const float4* wv0 = (const float4*)(v_w + (size_t)tid*CRD);
  const float4* wv1 = (const float4*)(v_w + (size_t)(tid+256)*CRD);
  float v0=0.f, v1=0.f;
#pragma unroll 8
  for (int i=0;i<CRD/4;++i){
    float4 xv=k4[i];
    float4 wa=wv0[i]; v0 += wa.x*xv.x+wa.y*xv.y+wa.z*xv.z+wa.w*xv.w;
    float4 wb=wv1[i]; v1 += wb.x*xv.x+wb.y*xv.y+wb.z*xv.z+wb.w*xv.w;
  }
  vbuf[((size_t)b*KT+t)*CH + tid]       = v0*sv;
  vbuf[((size_t)b*KT+t)*CH + 256 + tid] = v1*sv;
}

// ---------------- CPE: depthwise 3x3 over the 8x8 topk grid, v2 = v + cpe ----------------
__global__ __launch_bounds__(512) void cpe_kernel(const float* __restrict__ vbuf,
    const float* __restrict__ cpe_w, const float* __restrict__ cpe_b,
    float* __restrict__ v2)
{
  int b = blockIdx.x; int ch = threadIdx.x;
  float w[9];
#pragma unroll
  for (int j=0;j<9;++j) w[j] = cpe_w[ch*9+j];
  float bias = cpe_b[ch];
  const float* vb = vbuf + (size_t)b*KT*CH;
  float* vo = v2 + (size_t)b*KT*CH;
  for (int t=0;t<KT;++t){
    int gi=t>>3, gj=t&7;
    float s = bias;
#pragma unroll
    for (int dy=-1;dy<=1;++dy){
      int ii=gi+dy; if (ii<0||ii>=8) continue;
#pragma unroll
      for (int dx=-1;dx<=1;++dx){
        int jj=gj+dx; if (jj<0||jj>=8) continue;
        s += w[(dy+1)*3+(dx+1)] * vb[(ii*8+jj)*CH + ch];
      }
    }
    vo[t*CH+ch] = vb[t*CH+ch] + s;
  }
}

// ---------------- attention: dual softmax over kt=64 keys, out = attn @ v2 ----------------
__global__ __launch_bounds__(256) void attn_kernel(const float* __restrict__ Q,
    const float* __restrict__ kmat, const float* __restrict__ v2,
    const float* __restrict__ curv_top, const float* __restrict__ alpha_p,
    const float* __restrict__ beta_p, float* __restrict__ out)
{
  __shared__ float KsT[DHQ][KT];   // [32][64], lanes read KsT[d][lane]: conflict-free
  __shared__ float Vs[KT][DH];     // [64][64], lanes read Vs[t][lane]: conflict-free
  __shared__ float fm[KT];
  __shared__ float attn_s[4][KT];
  int bid = blockIdx.x;
  int chunk = bid & 63;
  int hh = (bid>>6) & 7;
  int b = bid>>9;
  int tid = threadIdx.x;
  float alpha = alpha_p[0], beta = beta_p[0];
  for (int i=tid;i<DHQ*KT;i+=256){
    int t = i & 63, d = i >> 6;
    KsT[d][t] = kmat[((size_t)b*KT+t)*CRD + hh*DHQ + d];
  }
  for (int i=tid;i<KT*DH;i+=256){
    int t = i >> 6, e = i & 63;
    Vs[t][e] = v2[((size_t)b*KT+t)*CH + hh*DH + e];
  }
  if (tid<KT) fm[tid] = 1.0f + alpha*curv_top[b*KT+tid];
  __syncthreads();
  int wid=tid>>6, lane=tid&63;
  for (int it=0; it<64; ++it){
    int n = chunk*256 + wid*64 + it;
    const float* q = Q + ((size_t)b*NSEQ + n)*CRD + hh*DHQ;
    float lg=0.f;
#pragma unroll
    for (int d=0;d<DHQ;++d) lg += q[d]*KsT[d][lane];   // lane owns key `lane`
    lg *= SCALEQ;
    float lg2 = lg*fm[lane];
    float m1 = wmax(lg);  float e1 = __expf(lg-m1);  float s1 = wsum(e1);
    float m2 = wmax(lg2); float e2 = __expf(lg2-m2); float s2 = wsum(e2);
    float at = beta*(e1/s1) + (1.0f-beta)*(e2/s2);
    attn_s[wid][lane]=at;
    float accv=0.f;
#pragma unroll 16
    for (int t=0;t<KT;++t) accv += attn_s[wid][t]*Vs[t][lane];  // lane owns out dim `lane`
    out[((size_t)b*NSEQ+n)*CH + hh*DH + lane] = accv;
  }
}

// ---------------- launch ----------------
extern "C" void kernel_launch(void* const* d_in, const int* in_sizes, int n_in,
                              void* d_out, int out_size, void* d_ws, size_t ws_size,
                              hipStream_t stream)
{
  (void)in_sizes; (void)n_in; (void)out_size; (void)ws_size;
  const float* x      = (const float*)d_in[0];
  const float* curv_w = (const float*)d_in[1];
  const float* gate_w1= (const float*)d_in[2];
  const float* gate_b1= (const float*)d_in[3];
  const float* gate_w2= (const float*)d_in[4];
  const float* gate_b2= (const float*)d_in[5];
  const float* q_w    = (const float*)d_in[6];
  const float* kvr_w  = (const float*)d_in[7];
  const float* kvr_b  = (const float*)d_in[8];
  const float* ln_g   = (const float*)d_in[9];
  const float* ln_b   = (const float*)d_in[10];
  const float* k_w    = (const float*)d_in[11];
  const float* v_w    = (const float*)d_in[12];
  const float* cpe_w  = (const float*)d_in[13];
  const float* cpe_b  = (const float*)d_in[14];
  const float* proj_w = (const float*)d_in[15];
  const float* proj_b = (const float*)d_in[16];
  const float* alpha  = (const float*)d_in[17];
  const float* beta   = (const float*)d_in[18];

  // workspace layout (bytes). Region A (268 MB) first holds {h_pre, T9, curv_raw,
  // score} (all dead after topk/score consumption), then is reused as attn_out.
  char* ws = (char*)d_ws;
  float* attn_out = (float*)(ws);
  float* h_pre    = (float*)(ws);                        // NTOK*256 f32 = 134217728 B
  float* T9       = (float*)(ws + 134217728);            // NTOK*9 f32   = 4718592 B
  float* curv_raw = (float*)(ws + 138936320);            // NTOK f32     = 524288 B
  float* score    = (float*)(ws + 139460608);            // NTOK f32     = 524288 B
  float* Qbuf     = (float*)(ws + 268435456);            // NTOK*256 f32 = 134217728 B
  char*  c0       = ws + 402653184;                      // small-buffer region
  float* curv_norm= (float*)(c0 + 0);                    // NTOK f32
  float* stats    = (float*)(c0 + 524288);               // 16 f32 (mean,rstd per b)
  int*   topk_idx = (int*)  (c0 + 524544);               // 512 i32
  float* topk_val = (float*)(c0 + 526592);               // 512 f32
  float* curv_top = (float*)(c0 + 528640);               // 512 f32
  float* kvbuf    = (float*)(c0 + 530688);               // 8*64*256 f32
  float* kmat     = (float*)(c0 + 1054976);              // 8*64*256 f32
  float* vbuf     = (float*)(c0 + 1579264);              // 8*64*512 f32
  float* v2buf    = (float*)(c0 + 2627840);              // 8*64*512 f32
  float* outp     = (float*)d_out;

  taps_kernel <<<NTOK/4, 256, 0, stream>>>(x, curv_w, T9);
  gemm_abt    <<<dim3(NTOK/GBM, CRD/GBN), 256, 0, stream>>>(x, gate_w1, gate_b1, h_pre, NTOK, CRD, CH);
  gemm_abt    <<<dim3(NTOK/GBM, CRD/GBN), 256, 0, stream>>>(x, q_w, nullptr, Qbuf, NTOK, CRD, CH);
  curv_combine<<<NTOK/256, 256, 0, stream>>>(T9, curv_raw);
  stats_kernel<<<NB, 256, 0, stream>>>(curv_raw, stats);
  score_kernel<<<NTOK/4, 256, 0, stream>>>(h_pre, gate_w2, gate_b2, curv_raw, stats, score, curv_norm);
  topk_kernel <<<NB, 256, 0, stream>>>(score, topk_idx, topk_val);
  kva_kernel  <<<NB*KT, 256, 0, stream>>>(x, topk_idx, kvr_w, kvr_b, ln_g, ln_b, curv_norm, kvbuf, curv_top);
  kvb_kernel  <<<NB*KT, 256, 0, stream>>>(kvbuf, k_w, v_w, topk_val, kmat, vbuf);
  cpe_kernel  <<<NB, 512, 0, stream>>>(vbuf, cpe_w, cpe_b, v2buf);
  attn_kernel <<<NB*NHEAD*(NSEQ/256), 256, 0, stream>>>(Qbuf, kmat, v2buf, curv_top, alpha, beta, attn_out);
  gemm_abt    <<<dim3(NTOK/GBM, CH/GBN), 256, 0, stream>>>(attn_out, proj_w, proj_b, outp, NTOK, CH, CH);
}

// Round 3
// 3016.810 us; speedup vs baseline: 1.3653x; 1.3653x over previous
//
#include <hip/hip_runtime.h>
#include <math.h>

// Problem constants (B=8, H=W=128, C=512, HEADS=8 -> kt=64 via _k_tokens)
#define NB     8
#define NSEQ   16384
#define NTOK   (NB*NSEQ)      // 131072
#define CH     512
#define CRD    256
#define NHEAD  8
#define DH     64
#define DHQ    32
#define KT     64
#define HH     128
#define WW     128
#define SCALEQ 0.17677669529663687f   // (64*0.5)^-0.5

// ---------------- wave helpers (wave = 64 lanes) ----------------
__device__ __forceinline__ float wsum(float v){
#pragma unroll
  for (int o=32;o;o>>=1) v += __shfl_xor(v,o,64);
  return v;
}
__device__ __forceinline__ float wmax(float v){
#pragma unroll
  for (int o=32;o;o>>=1) v = fmaxf(v,__shfl_xor(v,o,64));
  return v;
}

// ---------------- taps: T9[token][j] = sum_c x[token,c]*curv_w[c,j] ----------------
__global__ __launch_bounds__(256) void taps_kernel(const float* __restrict__ x,
    const float* __restrict__ curv_w, float* __restrict__ T9)
{
  __shared__ float ws_[CH*9];   // 18 KB
  int tid = threadIdx.x;
  for (int i=tid;i<CH*9;i+=256) ws_[i] = curv_w[i];
  __syncthreads();
  int wid = tid>>6, lane = tid&63;
  size_t token = (size_t)blockIdx.x*4 + wid;
  float acc[9] = {0,0,0,0,0,0,0,0,0};
#pragma unroll
  for (int i=0;i<8;++i){
    int c = lane + i*64;                    // stride-1 lanes: LDS addr 9c+j, gcd(9,32)=1 -> 2-way max (free)
    float xk = x[token*CH + c];
    const float* wp = &ws_[c*9];
#pragma unroll
    for (int j=0;j<9;++j) acc[j] += xk*wp[j];
  }
#pragma unroll
  for (int j=0;j<9;++j) acc[j] = wsum(acc[j]);
  if (lane==0){
#pragma unroll
    for (int j=0;j<9;++j) T9[token*9+j] = acc[j];
  }
}

// ---------------- generic fp32 GEMM: C[M,N] = A[M,K] @ B[N,K]^T (+bias) ----------------
// 128x128x16 tile, 8x8 per thread, global->register prefetch double buffer.
#define GBM 128
#define GBN 128
#define GBK 16
__global__ __launch_bounds__(256) void gemm_abt(
    const float* __restrict__ A, const float* __restrict__ Bm,
    const float* __restrict__ bias, float* __restrict__ C,
    int M, int N, int K)
{
  __shared__ float As[GBK][GBM+4];
  __shared__ float Bs[GBK][GBN+4];
  const int tid = threadIdx.x;
  const int bm = blockIdx.x * GBM;
  const int bn = blockIdx.y * GBN;
  const int tx = tid & 15;     // col group (split-quad: cols tx*4 and 64+tx*4)
  const int ty = tid >> 4;     // row group
  const int lr = tid >> 2;     // load row 0..63
  const int lf = tid & 3;      // float4 slot in 16-wide k

  const float* Ap0 = A  + (size_t)(bm+lr)*K    + lf*4;
  const float* Ap1 = A  + (size_t)(bm+lr+64)*K + lf*4;
  const float* Bp0 = Bm + (size_t)(bn+lr)*K    + lf*4;
  const float* Bp1 = Bm + (size_t)(bn+lr+64)*K + lf*4;

  float acc[8][8];
#pragma unroll
  for (int i=0;i<8;++i)
#pragma unroll
    for (int j=0;j<8;++j) acc[i][j]=0.f;

  // prologue: prefetch K-tile 0 into registers
  float4 ra0 = *(const float4*)(Ap0);
  float4 ra1 = *(const float4*)(Ap1);
  float4 rb0 = *(const float4*)(Bp0);
  float4 rb1 = *(const float4*)(Bp1);

  for (int k0=0;k0<K;k0+=GBK){
    __syncthreads();   // previous compute done reading LDS (no-op cost on iter 0)
    As[lf*4+0][lr]=ra0.x; As[lf*4+1][lr]=ra0.y; As[lf*4+2][lr]=ra0.z; As[lf*4+3][lr]=ra0.w;
    As[lf*4+0][lr+64]=ra1.x; As[lf*4+1][lr+64]=ra1.y; As[lf*4+2][lr+64]=ra1.z; As[lf*4+3][lr+64]=ra1.w;
    Bs[lf*4+0][lr]=rb0.x; Bs[lf*4+1][lr]=rb0.y; Bs[lf*4+2][lr]=rb0.z; Bs[lf*4+3][lr]=rb0.w;
    Bs[lf*4+0][lr+64]=rb1.x; Bs[lf*4+1][lr+64]=rb1.y; Bs[lf*4+2][lr+64]=rb1.z; Bs[lf*4+3][lr+64]=rb1.w;
    __syncthreads();   // LDS tile ready
    if (k0+GBK < K){   // issue next tile's global loads; latency hides under compute
      ra0 = *(const float4*)(Ap0 + k0+GBK);
      ra1 = *(const float4*)(Ap1 + k0+GBK);
      rb0 = *(const float4*)(Bp0 + k0+GBK);
      rb1 = *(const float4*)(Bp1 + k0+GBK);
    }
#pragma unroll
    for (int kk=0;kk<GBK;++kk){
      float a[8], b[8];
      *(float4*)&a[0] = *(const float4*)&As[kk][ty*4];
      *(float4*)&a[4] = *(const float4*)&As[kk][64+ty*4];
      *(float4*)&b[0] = *(const float4*)&Bs[kk][tx*4];
      *(float4*)&b[4] = *(const float4*)&Bs[kk][64+tx*4];
#pragma unroll
      for (int i=0;i<8;++i)
#pragma unroll
        for (int j=0;j<8;++j) acc[i][j] = fmaf(a[i], b[j], acc[i][j]);
    }
  }
#pragma unroll
  for (int i=0;i<8;++i){
    int row = bm + (i<4 ? ty*4+i : 64+ty*4+(i-4));
#pragma unroll
    for (int jg=0;jg<2;++jg){
      int col = bn + (jg==0 ? tx*4 : 64+tx*4);
      float b0=0.f,b1=0.f,b2v=0.f,b3=0.f;
      if (bias){ b0=bias[col]; b1=bias[col+1]; b2v=bias[col+2]; b3=bias[col+3]; }
      float4 o;
      o.x = acc[i][jg*4+0]+b0;
      o.y = acc[i][jg*4+1]+b1;
      o.z = acc[i][jg*4+2]+b2v;
      o.w = acc[i][jg*4+3]+b3;
      *(float4*)(C + (size_t)row*N + col) = o;
    }
  }
}

// ---------------- 9-tap spatial combine -> curv_raw (pre-LN) ----------------
__global__ __launch_bounds__(256) void curv_combine(const float* __restrict__ T9,
    float* __restrict__ curv_raw)
{
  int gid = blockIdx.x*256 + threadIdx.x;
  int b = gid >> 14;
  int p = gid & (NSEQ-1);
  int i = p >> 7;
  int k = p & (WW-1);
  float s = 0.f;
#pragma unroll
  for (int dy=-1;dy<=1;++dy){
    int ii = i+dy;
    if (ii<0||ii>=HH) continue;
#pragma unroll
    for (int dx=-1;dx<=1;++dx){
      int kk = k+dx;
      if (kk<0||kk>=WW) continue;
      int j = (dy+1)*3 + (dx+1);
      s += T9[((size_t)b*NSEQ + ii*WW + kk)*9 + j];
    }
  }
  curv_raw[gid] = s * (1.0f/512.0f);
}

// ---------------- per-batch LN stats over N=16384 ----------------
__global__ __launch_bounds__(256) void stats_kernel(const float* __restrict__ curv_raw,
    float* __restrict__ stats)
{
  __shared__ float red[256];
  int b = blockIdx.x, tid = threadIdx.x;
  const float* cr = curv_raw + (size_t)b*NSEQ;
  float s=0.f;
  for (int i=tid;i<NSEQ;i+=256) s += cr[i];
  red[tid]=s; __syncthreads();
  for (int st=128;st;st>>=1){ if(tid<st) red[tid]+=red[tid+st]; __syncthreads(); }
  float mean = red[0] * (1.0f/NSEQ);
  __syncthreads();
  float vs=0.f;
  for (int i=tid;i<NSEQ;i+=256){ float d=cr[i]-mean; vs += d*d; }
  red[tid]=vs; __syncthreads();
  for (int st=128;st;st>>=1){ if(tid<st) red[tid]+=red[tid+st]; __syncthreads(); }
  if (tid==0){ stats[2*b]=mean; stats[2*b+1]=rsqrtf(red[0]*(1.0f/NSEQ) + 1e-5f); }
}

// ---------------- gate layer-2 + sigmoid + normalized curv + score ----------------
__global__ __launch_bounds__(256) void score_kernel(const float* __restrict__ h_pre,
    const float* __restrict__ w2, const float* __restrict__ b2,
    const float* __restrict__ curv_raw, const float* __restrict__ stats,
    float* __restrict__ score, float* __restrict__ curv_norm)
{
  int tid=threadIdx.x; int wid=tid>>6, lane=tid&63;
  size_t token = (size_t)blockIdx.x*4 + wid;
  int b = (int)(token >> 14);
  const float* h = h_pre + token*CRD;
  float acc=0.f;
#pragma unroll
  for (int i=0;i<4;++i){
    int c = lane + i*64;
    float hv = fmaxf(h[c], 0.f);   // relu applied here (h_pre stored pre-activation)
    acc += hv * w2[c];
  }
  acc = wsum(acc);
  if (lane==0){
    float z = acc + b2[0];
    float gate = 1.0f/(1.0f + expf(-z));
    float cn = (curv_raw[token] - stats[2*b]) * stats[2*b+1];
    curv_norm[token] = cn;
    score[token] = 0.5f*(fabsf(cn) + gate);   // NOTE: score > 0 always (|.| + sigmoid)
  }
}

// ---------------- exact top-64 via two-stage bitonic sort on packed keys ----------------
// score > 0 so fp32 bits are order-monotonic as unsigned. key = bits<<32 | (~idx):
// descending key order == descending value, ties -> lowest index (jax.lax.top_k).
__device__ __forceinline__ void bitonic_sort_desc_1024(unsigned long long* keys, int tid){
  for (int k=2;k<=1024;k<<=1){
    for (int j=k>>1;j>0;j>>=1){
#pragma unroll
      for (int r=0;r<2;++r){
        int t = tid + r*512;
        int ixj = t ^ j;
        if (ixj > t){
          bool desc = ((t & k) == 0);
          unsigned long long a = keys[t], b = keys[ixj];
          bool sw = desc ? (a < b) : (a > b);
          if (sw){ keys[t]=b; keys[ixj]=a; }
        }
      }
      __syncthreads();
    }
  }
}

__global__ __launch_bounds__(512) void topk_stage1(const float* __restrict__ score,
    unsigned long long* __restrict__ cand)
{
  __shared__ unsigned long long keys[1024];   // 8 KB
  int blk = blockIdx.x;           // b*16 + chunk
  int b = blk >> 4, chunk = blk & 15;
  int tid = threadIdx.x;
  const float* sc = score + (size_t)b*NSEQ + chunk*1024;
#pragma unroll
  for (int r=0;r<2;++r){
    int t = tid + r*512;
    unsigned int vb = __float_as_uint(sc[t]);
    unsigned int gi = (unsigned)(chunk*1024 + t);
    keys[t] = ((unsigned long long)vb << 32) | (unsigned long long)(0xFFFFFFFFu - gi);
  }
  __syncthreads();
  bitonic_sort_desc_1024(keys, tid);
  if (tid < KT) cand[(size_t)blk*KT + tid] = keys[tid];
}

__global__ __launch_bounds__(512) void topk_stage2(const unsigned long long* __restrict__ cand,
    int* __restrict__ idx_out, float* __restrict__ val_out)
{
  __shared__ unsigned long long keys[1024];   // 16 chunks x 64 candidates
  int b = blockIdx.x; int tid = threadIdx.x;
  keys[tid]     = cand[(size_t)b*1024 + tid];
  keys[tid+512] = cand[(size_t)b*1024 + tid + 512];
  __syncthreads();
  bitonic_sort_desc_1024(keys, tid);
  if (tid < KT){
    unsigned long long kk = keys[tid];
    val_out[b*KT+tid] = __uint_as_float((unsigned)(kk >> 32));
    idx_out[b*KT+tid] = (int)(0xFFFFFFFFu - (unsigned)(kk & 0xFFFFFFFFu));
  }
}

// ---------------- kv = gelu(LN(x_topk @ kvr_w^T + kvr_b)); also gather curv_topk ----------------
__global__ __launch_bounds__(256) void kva_kernel(const float* __restrict__ x,
    const int* __restrict__ topk_idx, const float* __restrict__ kvr_w,
    const float* __restrict__ kvr_b, const float* __restrict__ ln_g,
    const float* __restrict__ ln_b, const float* __restrict__ curv_norm,
    float* __restrict__ kv, float* __restrict__ curv_top)
{
  __shared__ float xs[CH];
  __shared__ float red[CRD];
  int blk=blockIdx.x; int b=blk>>6, t=blk&63; int tid=threadIdx.x;
  int row = topk_idx[b*KT+t];
  const float* xr = x + ((size_t)b*NSEQ + row)*CH;
  xs[tid]=xr[tid]; xs[tid+256]=xr[tid+256];
  __syncthreads();
  float acc = kvr_b[tid];
  const float4* wr = (const float4*)(kvr_w + (size_t)tid*CH);
  const float4* x4 = (const float4*)xs;
#pragma unroll 8
  for (int i=0;i<CH/4;++i){
    float4 w4=wr[i]; float4 xv=x4[i];
    acc += w4.x*xv.x + w4.y*xv.y + w4.z*xv.z + w4.w*xv.w;
  }
  red[tid]=acc; __syncthreads();
  for (int st=128;st;st>>=1){ if(tid<st) red[tid]+=red[tid+st]; __syncthreads(); }
  float mean = red[0]*(1.0f/CRD);
  __syncthreads();
  float d = acc-mean;
  red[tid]=d*d; __syncthreads();
  for (int st=128;st;st>>=1){ if(tid<st) red[tid]+=red[tid+st]; __syncthreads(); }
  float rstd = rsqrtf(red[0]*(1.0f/CRD) + 1e-5f);
  float y = (acc-mean)*rstd*ln_g[tid] + ln_b[tid];
  float ge = 0.5f*y*(1.0f + erff(y*0.70710678118654752f));   // exact gelu
  kv[((size_t)b*KT+t)*CRD + tid] = ge;
  if (tid==0) curv_top[b*KT+t] = curv_norm[(size_t)b*NSEQ + row];
}

// ---------------- kmat = kv@k_w^T ; v = (kv@v_w^T) * score_topk ----------------
__global__ __launch_bounds__(256) void kvb_kernel(const float* __restrict__ kv,
    const float* __restrict__ k_w, const float* __restrict__ v_w,
    const float* __restrict__ topk_val, float* __restrict__ kmat,
    float* __restrict__ vbuf)
{
  __shared__ float ks[CRD];
  int blk=blockIdx.x; int b=blk>>6, t=blk&63; int tid=threadIdx.x;
  ks[tid] = kv[((size_t)b*KT+t)*CRD + tid];
  __syncthreads();
  float sv = topk_val[b*KT+t];
  const float4* k4 = (const float4*)ks;
  const float4* wk = (const float4*)(k_w + (size_t)tid*CRD);
  float a=0.f;
#pragma unroll 8
  for (int i=0;i<CRD/4;++i){ float4 w4=wk[i]; float4 xv=k4[i]; a += w4.x*xv.x+w4.y*xv.y+w4.z*xv.z+w4.w*xv.w; }
  kmat[((size_t)b*KT+t)*CRD + tid] = a;
  const float4* wv0 = (const float4*)(v_w + (size_t)tid*CRD);
  const float4* wv1 = (const float4*)(v_w + (size_t)(tid+256)*CRD);
  float v0=0.f, v1=0.f;
#pragma unroll 8
  for (int i=0;i<CRD/4;++i){
    float4 xv=k4[i];
    float4 wa=wv0[i]; v0 += wa.x*xv.x+wa.y*xv.y+wa.z*xv.z+wa.w*xv.w;
    float4 wb=wv1[i]; v1 += wb.x*xv.x+wb.y*xv.y+wb.z*xv.z+wb.w*xv.w;
  }
  vbuf[((size_t)b*KT+t)*CH + tid]       = v0*sv;
  vbuf[((size_t)b*KT+t)*CH + 256 + tid] = v1*sv;
}

// ---------------- CPE: depthwise 3x3 over the 8x8 topk grid, v2 = v + cpe ----------------
__global__ __launch_bounds__(512) void cpe_kernel(const float* __restrict__ vbuf,
    const float* __restrict__ cpe_w, const float* __restrict__ cpe_b,
    float* __restrict__ v2)
{
  int b = blockIdx.x; int ch = threadIdx.x;
  float w[9];
#pragma unroll
  for (int j=0;j<9;++j) w[j] = cpe_w[ch*9+j];
  float bias = cpe_b[ch];
  const float* vb = vbuf + (size_t)b*KT*CH;
  float* vo = v2 + (size_t)b*KT*CH;
  for (int t=0;t<KT;++t){
    int gi=t>>3, gj=t&7;
    float s = bias;
#pragma unroll
    for (int dy=-1;dy<=1;++dy){
      int ii=gi+dy; if (ii<0||ii>=8) continue;
#pragma unroll
      for (int dx=-1;dx<=1;++dx){
        int jj=gj+dx; if (jj<0||jj>=8) continue;
        s += w[(dy+1)*3+(dx+1)] * vb[(ii*8+jj)*CH + ch];
      }
    }
    vo[t*CH+ch] = vb[t*CH+ch] + s;
  }
}

// ---------------- attention: dual softmax over kt=64 keys, out = attn @ v2 ----------------
__global__ __launch_bounds__(256) void attn_kernel(const float* __restrict__ Q,
    const float* __restrict__ kmat, const float* __restrict__ v2,
    const float* __restrict__ curv_top, const float* __restrict__ alpha_p,
    const float* __restrict__ beta_p, float* __restrict__ out)
{
  __shared__ float KsT[DHQ][KT];   // [32][64], lanes read KsT[d][lane]: conflict-free
  __shared__ float Vs[KT][DH];     // [64][64], lanes read Vs[t][lane]: conflict-free
  __shared__ float fm[KT];
  __shared__ float attn_s[4][KT];
  int bid = blockIdx.x;
  int chunk = bid & 63;
  int hh = (bid>>6) & 7;
  int b = bid>>9;
  int tid = threadIdx.x;
  float alpha = alpha_p[0], beta = beta_p[0];
  for (int i=tid;i<DHQ*KT;i+=256){
    int t = i & 63, d = i >> 6;
    KsT[d][t] = kmat[((size_t)b*KT+t)*CRD + hh*DHQ + d];
  }
  for (int i=tid;i<KT*DH;i+=256){
    int t = i >> 6, e = i & 63;
    Vs[t][e] = v2[((size_t)b*KT+t)*CH + hh*DH + e];
  }
  if (tid<KT) fm[tid] = 1.0f + alpha*curv_top[b*KT+tid];
  __syncthreads();
  int wid=tid>>6, lane=tid&63;
  for (int it=0; it<64; ++it){
    int n = chunk*256 + wid*64 + it;
    const float* q = Q + ((size_t)b*NSEQ + n)*CRD + hh*DHQ;
    float lg=0.f;
#pragma unroll
    for (int d=0;d<DHQ;++d) lg += q[d]*KsT[d][lane];   // lane owns key `lane`
    lg *= SCALEQ;
    float lg2 = lg*fm[lane];
    float m1 = wmax(lg);  float e1 = __expf(lg-m1);  float s1 = wsum(e1);
    float m2 = wmax(lg2); float e2 = __expf(lg2-m2); float s2 = wsum(e2);
    float at = beta*(e1/s1) + (1.0f-beta)*(e2/s2);
    attn_s[wid][lane]=at;
    float accv=0.f;
#pragma unroll 16
    for (int t=0;t<KT;++t) accv += attn_s[wid][t]*Vs[t][lane];  // lane owns out dim `lane`
    out[((size_t)b*NSEQ+n)*CH + hh*DH + lane] = accv;
  }
}

// ---------------- launch ----------------
extern "C" void kernel_launch(void* const* d_in, const int* in_sizes, int n_in,
                              void* d_out, int out_size, void* d_ws, size_t ws_size,
                              hipStream_t stream)
{
  (void)in_sizes; (void)n_in; (void)out_size; (void)ws_size;
  const float* x      = (const float*)d_in[0];
  const float* curv_w = (const float*)d_in[1];
  const float* gate_w1= (const float*)d_in[2];
  const float* gate_b1= (const float*)d_in[3];
  const float* gate_w2= (const float*)d_in[4];
  const float* gate_b2= (const float*)d_in[5];
  const float* q_w    = (const float*)d_in[6];
  const float* kvr_w  = (const float*)d_in[7];
  const float* kvr_b  = (const float*)d_in[8];
  const float* ln_g   = (const float*)d_in[9];
  const float* ln_b   = (const float*)d_in[10];
  const float* k_w    = (const float*)d_in[11];
  const float* v_w    = (const float*)d_in[12];
  const float* cpe_w  = (const float*)d_in[13];
  const float* cpe_b  = (const float*)d_in[14];
  const float* proj_w = (const float*)d_in[15];
  const float* proj_b = (const float*)d_in[16];
  const float* alpha  = (const float*)d_in[17];
  const float* beta   = (const float*)d_in[18];

  // workspace layout (bytes). Region A (268 MB) first holds {h_pre, T9, curv_raw,
  // score} (all dead after topk/score consumption), then is reused as attn_out.
  // cand (64 KB) reuses the dead T9 region (T9 consumed by curv_combine before topk).
  char* ws = (char*)d_ws;
  float* attn_out = (float*)(ws);
  float* h_pre    = (float*)(ws);                        // NTOK*256 f32 = 134217728 B
  float* T9       = (float*)(ws + 134217728);            // NTOK*9 f32   = 4718592 B
  unsigned long long* cand = (unsigned long long*)(ws + 134217728);  // 8*16*64 u64 = 64 KB (aliases dead T9)
  float* curv_raw = (float*)(ws + 138936320);            // NTOK f32     = 524288 B
  float* score    = (float*)(ws + 139460608);            // NTOK f32     = 524288 B
  float* Qbuf     = (float*)(ws + 268435456);            // NTOK*256 f32 = 134217728 B
  char*  c0       = ws + 402653184;                      // small-buffer region
  float* curv_norm= (float*)(c0 + 0);                    // NTOK f32
  float* stats    = (float*)(c0 + 524288);               // 16 f32 (mean,rstd per b)
  int*   topk_idx = (int*)  (c0 + 524544);               // 512 i32
  float* topk_val = (float*)(c0 + 526592);               // 512 f32
  float* curv_top = (float*)(c0 + 528640);               // 512 f32
  float* kvbuf    = (float*)(c0 + 530688);               // 8*64*256 f32
  float* kmat     = (float*)(c0 + 1054976);              // 8*64*256 f32
  float* vbuf     = (float*)(c0 + 1579264);              // 8*64*512 f32
  float* v2buf    = (float*)(c0 + 2627840);              // 8*64*512 f32
  float* outp     = (float*)d_out;

  taps_kernel <<<NTOK/4, 256, 0, stream>>>(x, curv_w, T9);
  gemm_abt    <<<dim3(NTOK/GBM, CRD/GBN), 256, 0, stream>>>(x, gate_w1, gate_b1, h_pre, NTOK, CRD, CH);
  gemm_abt    <<<dim3(NTOK/GBM, CRD/GBN), 256, 0, stream>>>(x, q_w, nullptr, Qbuf, NTOK, CRD, CH);
  curv_combine<<<NTOK/256, 256, 0, stream>>>(T9, curv_raw);
  stats_kernel<<<NB, 256, 0, stream>>>(curv_raw, stats);
  score_kernel<<<NTOK/4, 256, 0, stream>>>(h_pre, gate_w2, gate_b2, curv_raw, stats, score, curv_norm);
  topk_stage1 <<<NB*16, 512, 0, stream>>>(score, cand);
  topk_stage2 <<<NB, 512, 0, stream>>>(cand, topk_idx, topk_val);
  kva_kernel  <<<NB*KT, 256, 0, stream>>>(x, topk_idx, kvr_w, kvr_b, ln_g, ln_b, curv_norm, kvbuf, curv_top);
  kvb_kernel  <<<NB*KT, 256, 0, stream>>>(kvbuf, k_w, v_w, topk_val, kmat, vbuf);
  cpe_kernel  <<<NB, 512, 0, stream>>>(vbuf, cpe_w, cpe_b, v2buf);
  attn_kernel <<<NB*NHEAD*(NSEQ/256), 256, 0, stream>>>(Qbuf, kmat, v2buf, curv_top, alpha, beta, attn_out);
  gemm_abt    <<<dim3(NTOK/GBM, CH/GBN), 256, 0, stream>>>(attn_out, proj_w, proj_b, outp, NTOK, CH, CH);
}

// Round 4
// 1970.832 us; speedup vs baseline: 2.0899x; 1.5307x over previous
//
#include <hip/hip_runtime.h>
#include <hip/hip_bf16.h>
#include <math.h>

// Problem constants (B=8, H=W=128, C=512, HEADS=8 -> kt=64 via _k_tokens)
#define NB     8
#define NSEQ   16384
#define NTOK   (NB*NSEQ)      // 131072
#define CH     512
#define CRD    256
#define NHEAD  8
#define DH     64
#define DHQ    32
#define KT     64
#define HH     128
#define WW     128
#define SCALEQ 0.17677669529663687f   // (64*0.5)^-0.5

typedef __attribute__((ext_vector_type(8))) short bf8_t;   // 8 bf16 (4 VGPR) MFMA operand
typedef __attribute__((ext_vector_type(4))) float f32x4;   // MFMA accumulator

// ---------------- wave helpers (wave = 64 lanes) ----------------
__device__ __forceinline__ float wsum(float v){
#pragma unroll
  for (int o=32;o;o>>=1) v += __shfl_xor(v,o,64);
  return v;
}
__device__ __forceinline__ float wmax(float v){
#pragma unroll
  for (int o=32;o;o>>=1) v = fmaxf(v,__shfl_xor(v,o,64));
  return v;
}

__device__ __forceinline__ unsigned short bf_bits(float f){
  __hip_bfloat16 h = __float2bfloat16(f);      // RNE; compiler emits v_cvt_pk_bf16_f32
  return __builtin_bit_cast(unsigned short, h);
}
__device__ __forceinline__ float bf_back(unsigned short s){
  return __uint_as_float(((unsigned)s) << 16);
}

// ---------------- taps: T9[token][j] = sum_c x[token,c]*curv_w[c,j] ----------------
__global__ __launch_bounds__(256) void taps_kernel(const float* __restrict__ x,
    const float* __restrict__ curv_w, float* __restrict__ T9)
{
  __shared__ float ws_[CH*9];   // 18 KB
  int tid = threadIdx.x;
  for (int i=tid;i<CH*9;i+=256) ws_[i] = curv_w[i];
  __syncthreads();
  int wid = tid>>6, lane = tid&63;
  size_t token = (size_t)blockIdx.x*4 + wid;
  float acc[9] = {0,0,0,0,0,0,0,0,0};
#pragma unroll
  for (int i=0;i<8;++i){
    int c = lane + i*64;
    float xk = x[token*CH + c];
    const float* wp = &ws_[c*9];
#pragma unroll
    for (int j=0;j<9;++j) acc[j] += xk*wp[j];
  }
#pragma unroll
  for (int j=0;j<9;++j) acc[j] = wsum(acc[j]);
  if (lane==0){
#pragma unroll
    for (int j=0;j<9;++j) T9[token*9+j] = acc[j];
  }
}

// ---------------- split-bf16 MFMA GEMM: C[M,N] = A[M,K] @ W[N,K]^T (+bias) ----------------
// 3-term split: A=Ah+Al, W=Wh+Wl (bf16 RNE hi, RNE lo of residual);
// C ~= Ah*Wh + Ah*Wl + Al*Wh  (residual ~2^-17 rel -- fp32-class accuracy).
// Conversion happens in-kernel during LDS staging: no extra global buffers/traffic.
// Tile 128x128xBK32, 4 waves (2x2 of 64x64), mfma_f32_16x16x32_bf16.
// LDS rows padded to 48 bf16 (96 B): 16B-aligned, bank-uniform fragment reads.
#define LSTR 48
__global__ __launch_bounds__(256) void gemm3bf(
    const float* __restrict__ A, const float* __restrict__ Wm,
    const float* __restrict__ bias, float* __restrict__ C,
    int N, int K, int nbx_shift)
{
  __shared__ unsigned short Ah[128*LSTR], Al[128*LSTR], Bh[128*LSTR], Bl[128*LSTR]; // 48 KB
  const int tid = threadIdx.x;
  const int bid = blockIdx.x;
  const int nbx_mask = (1<<nbx_shift) - 1;
  const int bm = (bid >> nbx_shift) * 128;   // n fastest: adjacent blocks share A panel in L2
  const int bn = (bid & nbx_mask) * 128;

  const int w    = tid >> 6;        // wave 0..3
  const int lane = tid & 63;
  const int wr   = (w >> 1) * 64;   // wave row offset in tile
  const int wc   = (w & 1) * 64;    // wave col offset
  const int fr   = lane & 15;       // fragment row/col
  const int fs   = lane >> 4;       // fragment k-slot (0..3)

  f32x4 acc[4][4];
#pragma unroll
  for (int mt=0; mt<4; ++mt)
#pragma unroll
    for (int nt=0; nt<4; ++nt) acc[mt][nt] = (f32x4){0.f,0.f,0.f,0.f};

  // staging assignment: chunk c = i*256+tid -> row=c>>3 (0..127), ks=c&7 (float4 slot in BK=32)
  float4 ra[4], rb[4];
#pragma unroll
  for (int i=0;i<4;++i){
    int c = i*256 + tid; int row = c>>3, ks = c&7;
    ra[i] = *(const float4*)(A  + (size_t)(bm+row)*K + ks*4);
    rb[i] = *(const float4*)(Wm + (size_t)(bn+row)*K + ks*4);
  }

  for (int k0=0; k0<K; k0+=32){
    __syncthreads();   // everyone done reading LDS from previous step
#pragma unroll
    for (int i=0;i<4;++i){
      int c = i*256 + tid; int row = c>>3, ks = c&7;
      float4 va = ra[i], vb = rb[i];
      ushort4 ah4, al4, bh4, bl4;
      ah4.x = bf_bits(va.x); al4.x = bf_bits(va.x - bf_back(ah4.x));
      ah4.y = bf_bits(va.y); al4.y = bf_bits(va.y - bf_back(ah4.y));
      ah4.z = bf_bits(va.z); al4.z = bf_bits(va.z - bf_back(ah4.z));
      ah4.w = bf_bits(va.w); al4.w = bf_bits(va.w - bf_back(ah4.w));
      bh4.x = bf_bits(vb.x); bl4.x = bf_bits(vb.x - bf_back(bh4.x));
      bh4.y = bf_bits(vb.y); bl4.y = bf_bits(vb.y - bf_back(bh4.y));
      bh4.z = bf_bits(vb.z); bl4.z = bf_bits(vb.z - bf_back(bh4.z));
      bh4.w = bf_bits(vb.w); bl4.w = bf_bits(vb.w - bf_back(bh4.w));
      *(ushort4*)&Ah[row*LSTR + ks*4] = ah4;
      *(ushort4*)&Al[row*LSTR + ks*4] = al4;
      *(ushort4*)&Bh[row*LSTR + ks*4] = bh4;
      *(ushort4*)&Bl[row*LSTR + ks*4] = bl4;
    }
    __syncthreads();   // LDS tiles ready
    if (k0 + 32 < K){  // prefetch next step's globals; latency hides under MFMAs
#pragma unroll
      for (int i=0;i<4;++i){
        int c = i*256 + tid; int row = c>>3, ks = c&7;
        ra[i] = *(const float4*)(A  + (size_t)(bm+row)*K + k0+32 + ks*4);
        rb[i] = *(const float4*)(Wm + (size_t)(bn+row)*K + k0+32 + ks*4);
      }
    }
    // fragments: A row = wr+mt*16+fr, k-slot fs  (mfma 16x16x32 bf16 layout:
    // A: row=l%16, k=(l/16)*8+j ; B: col=l%16, k=(l/16)*8+j ; D: col=l&15, row=(l>>4)*4+reg)
    bf8_t ahf[4], alf[4];
#pragma unroll
    for (int mt=0; mt<4; ++mt){
      int r = wr + mt*16 + fr;
      ahf[mt] = *(const bf8_t*)&Ah[r*LSTR + fs*8];
      alf[mt] = *(const bf8_t*)&Al[r*LSTR + fs*8];
    }
#pragma unroll
    for (int nt=0; nt<4; ++nt){
      int cix = wc + nt*16 + fr;
      bf8_t bhf = *(const bf8_t*)&Bh[cix*LSTR + fs*8];
      bf8_t blf = *(const bf8_t*)&Bl[cix*LSTR + fs*8];
#pragma unroll
      for (int mt=0; mt<4; ++mt){
        acc[mt][nt] = __builtin_amdgcn_mfma_f32_16x16x32_bf16(ahf[mt], bhf, acc[mt][nt], 0,0,0);
        acc[mt][nt] = __builtin_amdgcn_mfma_f32_16x16x32_bf16(ahf[mt], blf, acc[mt][nt], 0,0,0);
        acc[mt][nt] = __builtin_amdgcn_mfma_f32_16x16x32_bf16(alf[mt], bhf, acc[mt][nt], 0,0,0);
      }
    }
  }
  // epilogue: D col = lane&15, row = (lane>>4)*4 + reg  (m89-verified)
#pragma unroll
  for (int nt=0; nt<4; ++nt){
    int col = bn + wc + nt*16 + fr;
    float bv = bias ? bias[col] : 0.f;
#pragma unroll
    for (int mt=0; mt<4; ++mt){
      int row0 = bm + wr + mt*16 + fs*4;
#pragma unroll
      for (int j=0;j<4;++j){
        C[(size_t)(row0+j)*N + col] = acc[mt][nt][j] + bv;
      }
    }
  }
}

// ---------------- 9-tap spatial combine -> curv_raw (pre-LN) ----------------
__global__ __launch_bounds__(256) void curv_combine(const float* __restrict__ T9,
    float* __restrict__ curv_raw)
{
  int gid = blockIdx.x*256 + threadIdx.x;
  int b = gid >> 14;
  int p = gid & (NSEQ-1);
  int i = p >> 7;
  int k = p & (WW-1);
  float s = 0.f;
#pragma unroll
  for (int dy=-1;dy<=1;++dy){
    int ii = i+dy;
    if (ii<0||ii>=HH) continue;
#pragma unroll
    for (int dx=-1;dx<=1;++dx){
      int kk = k+dx;
      if (kk<0||kk>=WW) continue;
      int j = (dy+1)*3 + (dx+1);
      s += T9[((size_t)b*NSEQ + ii*WW + kk)*9 + j];
    }
  }
  curv_raw[gid] = s * (1.0f/512.0f);
}

// ---------------- per-batch LN stats over N=16384 ----------------
__global__ __launch_bounds__(256) void stats_kernel(const float* __restrict__ curv_raw,
    float* __restrict__ stats)
{
  __shared__ float red[256];
  int b = blockIdx.x, tid = threadIdx.x;
  const float* cr = curv_raw + (size_t)b*NSEQ;
  float s=0.f;
  for (int i=tid;i<NSEQ;i+=256) s += cr[i];
  red[tid]=s; __syncthreads();
  for (int st=128;st;st>>=1){ if(tid<st) red[tid]+=red[tid+st]; __syncthreads(); }
  float mean = red[0] * (1.0f/NSEQ);
  __syncthreads();
  float vs=0.f;
  for (int i=tid;i<NSEQ;i+=256){ float d=cr[i]-mean; vs += d*d; }
  red[tid]=vs; __syncthreads();
  for (int st=128;st;st>>=1){ if(tid<st) red[tid]+=red[tid+st]; __syncthreads(); }
  if (tid==0){ stats[2*b]=mean; stats[2*b+1]=rsqrtf(red[0]*(1.0f/NSEQ) + 1e-5f); }
}

// ---------------- gate layer-2 + sigmoid + normalized curv + score ----------------
__global__ __launch_bounds__(256) void score_kernel(const float* __restrict__ h_pre,
    const float* __restrict__ w2, const float* __restrict__ b2,
    const float* __restrict__ curv_raw, const float* __restrict__ stats,
    float* __restrict__ score, float* __restrict__ curv_norm)
{
  int tid=threadIdx.x; int wid=tid>>6, lane=tid&63;
  size_t token = (size_t)blockIdx.x*4 + wid;
  int b = (int)(token >> 14);
  const float* h = h_pre + token*CRD;
  float acc=0.f;
#pragma unroll
  for (int i=0;i<4;++i){
    int c = lane + i*64;
    float hv = fmaxf(h[c], 0.f);   // relu applied here (h_pre stored pre-activation)
    acc += hv * w2[c];
  }
  acc = wsum(acc);
  if (lane==0){
    float z = acc + b2[0];
    float gate = 1.0f/(1.0f + expf(-z));
    float cn = (curv_raw[token] - stats[2*b]) * stats[2*b+1];
    curv_norm[token] = cn;
    score[token] = 0.5f*(fabsf(cn) + gate);   // NOTE: score > 0 always (|.| + sigmoid)
  }
}

// ---------------- exact top-64 via two-stage bitonic sort on packed keys ----------------
__device__ __forceinline__ void bitonic_sort_desc_1024(unsigned long long* keys, int tid){
  for (int k=2;k<=1024;k<<=1){
    for (int j=k>>1;j>0;j>>=1){
#pragma unroll
      for (int r=0;r<2;++r){
        int t = tid + r*512;
        int ixj = t ^ j;
        if (ixj > t){
          bool desc = ((t & k) == 0);
          unsigned long long a = keys[t], b = keys[ixj];
          bool sw = desc ? (a < b) : (a > b);
          if (sw){ keys[t]=b; keys[ixj]=a; }
        }
      }
      __syncthreads();
    }
  }
}

__global__ __launch_bounds__(512) void topk_stage1(const float* __restrict__ score,
    unsigned long long* __restrict__ cand)
{
  __shared__ unsigned long long keys[1024];   // 8 KB
  int blk = blockIdx.x;           // b*16 + chunk
  int b = blk >> 4, chunk = blk & 15;
  int tid = threadIdx.x;
  const float* sc = score + (size_t)b*NSEQ + chunk*1024;
#pragma unroll
  for (int r=0;r<2;++r){
    int t = tid + r*512;
    unsigned int vb = __float_as_uint(sc[t]);
    unsigned int gi = (unsigned)(chunk*1024 + t);
    keys[t] = ((unsigned long long)vb << 32) | (unsigned long long)(0xFFFFFFFFu - gi);
  }
  __syncthreads();
  bitonic_sort_desc_1024(keys, tid);
  if (tid < KT) cand[(size_t)blk*KT + tid] = keys[tid];
}

__global__ __launch_bounds__(512) void topk_stage2(const unsigned long long* __restrict__ cand,
    int* __restrict__ idx_out, float* __restrict__ val_out)
{
  __shared__ unsigned long long keys[1024];   // 16 chunks x 64 candidates
  int b = blockIdx.x; int tid = threadIdx.x;
  keys[tid]     = cand[(size_t)b*1024 + tid];
  keys[tid+512] = cand[(size_t)b*1024 + tid + 512];
  __syncthreads();
  bitonic_sort_desc_1024(keys, tid);
  if (tid < KT){
    unsigned long long kk = keys[tid];
    val_out[b*KT+tid] = __uint_as_float((unsigned)(kk >> 32));
    idx_out[b*KT+tid] = (int)(0xFFFFFFFFu - (unsigned)(kk & 0xFFFFFFFFu));
  }
}

// ---------------- kv = gelu(LN(x_topk @ kvr_w^T + kvr_b)); also gather curv_topk ----------------
__global__ __launch_bounds__(256) void kva_kernel(const float* __restrict__ x,
    const int* __restrict__ topk_idx, const float* __restrict__ kvr_w,
    const float* __restrict__ kvr_b, const float* __restrict__ ln_g,
    const float* __restrict__ ln_b, const float* __restrict__ curv_norm,
    float* __restrict__ kv, float* __restrict__ curv_top)
{
  __shared__ float xs[CH];
  __shared__ float red[CRD];
  int blk=blockIdx.x; int b=blk>>6, t=blk&63; int tid=threadIdx.x;
  int row = topk_idx[b*KT+t];
  const float* xr = x + ((size_t)b*NSEQ + row)*CH;
  xs[tid]=xr[tid]; xs[tid+256]=xr[tid+256];
  __syncthreads();
  float acc = kvr_b[tid];
  const float4* wr = (const float4*)(kvr_w + (size_t)tid*CH);
  const float4* x4 = (const float4*)xs;
#pragma unroll 8
  for (int i=0;i<CH/4;++i){
    float4 w4=wr[i]; float4 xv=x4[i];
    acc += w4.x*xv.x + w4.y*xv.y + w4.z*xv.z + w4.w*xv.w;
  }
  red[tid]=acc; __syncthreads();
  for (int st=128;st;st>>=1){ if(tid<st) red[tid]+=red[tid+st]; __syncthreads(); }
  float mean = red[0]*(1.0f/CRD);
  __syncthreads();
  float d = acc-mean;
  red[tid]=d*d; __syncthreads();
  for (int st=128;st;st>>=1){ if(tid<st) red[tid]+=red[tid+st]; __syncthreads(); }
  float rstd = rsqrtf(red[0]*(1.0f/CRD) + 1e-5f);
  float y = (acc-mean)*rstd*ln_g[tid] + ln_b[tid];
  float ge = 0.5f*y*(1.0f + erff(y*0.70710678118654752f));   // exact gelu
  kv[((size_t)b*KT+t)*CRD + tid] = ge;
  if (tid==0) curv_top[b*KT+t] = curv_norm[(size_t)b*NSEQ + row];
}

// ---------------- kmat = kv@k_w^T ; v = (kv@v_w^T) * score_topk ----------------
__global__ __launch_bounds__(256) void kvb_kernel(const float* __restrict__ kv,
    const float* __restrict__ k_w, const float* __restrict__ v_w,
    const float* __restrict__ topk_val, float* __restrict__ kmat,
    float* __restrict__ vbuf)
{
  __shared__ float ks[CRD];
  int blk=blockIdx.x; int b=blk>>6, t=blk&63; int tid=threadIdx.x;
  ks[tid] = kv[((size_t)b*KT+t)*CRD + tid];
  __syncthreads();
  float sv = topk_val[b*KT+t];
  const float4* k4 = (const float4*)ks;
  const float4* wk = (const float4*)(k_w + (size_t)tid*CRD);
  float a=0.f;
#pragma unroll 8
  for (int i=0;i<CRD/4;++i){ float4 w4=wk[i]; float4 xv=k4[i]; a += w4.x*xv.x+w4.y*xv.y+w4.z*xv.z+w4.w*xv.w; }
  kmat[((size_t)b*KT+t)*CRD + tid] = a;
  const float4* wv0 = (const float4*)(v_w + (size_t)tid*CRD);
  const float4* wv1 = (const float4*)(v_w + (size_t)(tid+256)*CRD);
  float v0=0.f, v1=0.f;
#pragma unroll 8
  for (int i=0;i<CRD/4;++i){
    float4 xv=k4[i];
    float4 wa=wv0[i]; v0 += wa.x*xv.x+wa.y*xv.y+wa.z*xv.z+wa.w*xv.w;
    float4 wb=wv1[i]; v1 += wb.x*xv.x+wb.y*xv.y+wb.z*xv.z+wb.w*xv.w;
  }
  vbuf[((size_t)b*KT+t)*CH + tid]       = v0*sv;
  vbuf[((size_t)b*KT+t)*CH + 256 + tid] = v1*sv;
}

// ---------------- CPE: depthwise 3x3 over the 8x8 topk grid, v2 = v + cpe ----------------
__global__ __launch_bounds__(512) void cpe_kernel(const float* __restrict__ vbuf,
    const float* __restrict__ cpe_w, const float* __restrict__ cpe_b,
    float* __restrict__ v2)
{
  int b = blockIdx.x; int ch = threadIdx.x;
  float w[9];
#pragma unroll
  for (int j=0;j<9;++j) w[j] = cpe_w[ch*9+j];
  float bias = cpe_b[ch];
  const float* vb = vbuf + (size_t)b*KT*CH;
  float* vo = v2 + (size_t)b*KT*CH;
  for (int t=0;t<KT;++t){
    int gi=t>>3, gj=t&7;
    float s = bias;
#pragma unroll
    for (int dy=-1;dy<=1;++dy){
      int ii=gi+dy; if (ii<0||ii>=8) continue;
#pragma unroll
      for (int dx=-1;dx<=1;++dx){
        int jj=gj+dx; if (jj<0||jj>=8) continue;
        s += w[(dy+1)*3+(dx+1)] * vb[(ii*8+jj)*CH + ch];
      }
    }
    vo[t*CH+ch] = vb[t*CH+ch] + s;
  }
}

// ---------------- attention: dual softmax over kt=64 keys, out = attn @ v2 ----------------
__global__ __launch_bounds__(256) void attn_kernel(const float* __restrict__ Q,
    const float* __restrict__ kmat, const float* __restrict__ v2,
    const float* __restrict__ curv_top, const float* __restrict__ alpha_p,
    const float* __restrict__ beta_p, float* __restrict__ out)
{
  __shared__ float KsT[DHQ][KT];   // [32][64], lanes read KsT[d][lane]: conflict-free
  __shared__ float Vs[KT][DH];     // [64][64], lanes read Vs[t][lane]: conflict-free
  __shared__ float fm[KT];
  __shared__ float attn_s[4][KT];
  int bid = blockIdx.x;
  int chunk = bid & 63;
  int hh = (bid>>6) & 7;
  int b = bid>>9;
  int tid = threadIdx.x;
  float alpha = alpha_p[0], beta = beta_p[0];
  for (int i=tid;i<DHQ*KT;i+=256){
    int t = i & 63, d = i >> 6;
    KsT[d][t] = kmat[((size_t)b*KT+t)*CRD + hh*DHQ + d];
  }
  for (int i=tid;i<KT*DH;i+=256){
    int t = i >> 6, e = i & 63;
    Vs[t][e] = v2[((size_t)b*KT+t)*CH + hh*DH + e];
  }
  if (tid<KT) fm[tid] = 1.0f + alpha*curv_top[b*KT+tid];
  __syncthreads();
  int wid=tid>>6, lane=tid&63;
  for (int it=0; it<64; ++it){
    int n = chunk*256 + wid*64 + it;
    const float* q = Q + ((size_t)b*NSEQ + n)*CRD + hh*DHQ;
    float lg=0.f;
#pragma unroll
    for (int d=0;d<DHQ;++d) lg += q[d]*KsT[d][lane];   // lane owns key `lane`
    lg *= SCALEQ;
    float lg2 = lg*fm[lane];
    float m1 = wmax(lg);  float e1 = __expf(lg-m1);  float s1 = wsum(e1);
    float m2 = wmax(lg2); float e2 = __expf(lg2-m2); float s2 = wsum(e2);
    float at = beta*(e1/s1) + (1.0f-beta)*(e2/s2);
    attn_s[wid][lane]=at;
    float accv=0.f;
#pragma unroll 16
    for (int t=0;t<KT;++t) accv += attn_s[wid][t]*Vs[t][lane];  // lane owns out dim `lane`
    out[((size_t)b*NSEQ+n)*CH + hh*DH + lane] = accv;
  }
}

// ---------------- launch ----------------
extern "C" void kernel_launch(void* const* d_in, const int* in_sizes, int n_in,
                              void* d_out, int out_size, void* d_ws, size_t ws_size,
                              hipStream_t stream)
{
  (void)in_sizes; (void)n_in; (void)out_size; (void)ws_size;
  const float* x      = (const float*)d_in[0];
  const float* curv_w = (const float*)d_in[1];
  const float* gate_w1= (const float*)d_in[2];
  const float* gate_b1= (const float*)d_in[3];
  const float* gate_w2= (const float*)d_in[4];
  const float* gate_b2= (const float*)d_in[5];
  const float* q_w    = (const float*)d_in[6];
  const float* kvr_w  = (const float*)d_in[7];
  const float* kvr_b  = (const float*)d_in[8];
  const float* ln_g   = (const float*)d_in[9];
  const float* ln_b   = (const float*)d_in[10];
  const float* k_w    = (const float*)d_in[11];
  const float* v_w    = (const float*)d_in[12];
  const float* cpe_w  = (const float*)d_in[13];
  const float* cpe_b  = (const float*)d_in[14];
  const float* proj_w = (const float*)d_in[15];
  const float* proj_b = (const float*)d_in[16];
  const float* alpha  = (const float*)d_in[17];
  const float* beta   = (const float*)d_in[18];

  // workspace layout (bytes). Region A (268 MB) first holds {h_pre, T9, curv_raw,
  // score} (all dead after topk/score consumption), then is reused as attn_out.
  // cand (64 KB) reuses the dead T9 region (T9 consumed by curv_combine before topk).
  char* ws = (char*)d_ws;
  float* attn_out = (float*)(ws);
  float* h_pre    = (float*)(ws);                        // NTOK*256 f32 = 134217728 B
  float* T9       = (float*)(ws + 134217728);            // NTOK*9 f32   = 4718592 B
  unsigned long long* cand = (unsigned long long*)(ws + 134217728);  // 64 KB (aliases dead T9)
  float* curv_raw = (float*)(ws + 138936320);            // NTOK f32     = 524288 B
  float* score    = (float*)(ws + 139460608);            // NTOK f32     = 524288 B
  float* Qbuf     = (float*)(ws + 268435456);            // NTOK*256 f32 = 134217728 B
  char*  c0       = ws + 402653184;                      // small-buffer region
  float* curv_norm= (float*)(c0 + 0);                    // NTOK f32
  float* stats    = (float*)(c0 + 524288);               // 16 f32 (mean,rstd per b)
  int*   topk_idx = (int*)  (c0 + 524544);               // 512 i32
  float* topk_val = (float*)(c0 + 526592);               // 512 f32
  float* curv_top = (float*)(c0 + 528640);               // 512 f32
  float* kvbuf    = (float*)(c0 + 530688);               // 8*64*256 f32
  float* kmat     = (float*)(c0 + 1054976);              // 8*64*256 f32
  float* vbuf     = (float*)(c0 + 1579264);              // 8*64*512 f32
  float* v2buf    = (float*)(c0 + 2627840);              // 8*64*512 f32
  float* outp     = (float*)d_out;

  taps_kernel <<<NTOK/4, 256, 0, stream>>>(x, curv_w, T9);
  gemm3bf     <<<(NTOK/128)*2, 256, 0, stream>>>(x, gate_w1, gate_b1, h_pre, CRD, CH, 1);
  gemm3bf     <<<(NTOK/128)*2, 256, 0, stream>>>(x, q_w, nullptr, Qbuf, CRD, CH, 1);
  curv_combine<<<NTOK/256, 256, 0, stream>>>(T9, curv_raw);
  stats_kernel<<<NB, 256, 0, stream>>>(curv_raw, stats);
  score_kernel<<<NTOK/4, 256, 0, stream>>>(h_pre, gate_w2, gate_b2, curv_raw, stats, score, curv_norm);
  topk_stage1 <<<NB*16, 512, 0, stream>>>(score, cand);
  topk_stage2 <<<NB, 512, 0, stream>>>(cand, topk_idx, topk_val);
  kva_kernel  <<<NB*KT, 256, 0, stream>>>(x, topk_idx, kvr_w, kvr_b, ln_g, ln_b, curv_norm, kvbuf, curv_top);
  kvb_kernel  <<<NB*KT, 256, 0, stream>>>(kvbuf, k_w, v_w, topk_val, kmat, vbuf);
  cpe_kernel  <<<NB, 512, 0, stream>>>(vbuf, cpe_w, cpe_b, v2buf);
  attn_kernel <<<NB*NHEAD*(NSEQ/256), 256, 0, stream>>>(Qbuf, kmat, v2buf, curv_top, alpha, beta, attn_out);
  gemm3bf     <<<(NTOK/128)*4, 256, 0, stream>>>(attn_out, proj_w, proj_b, outp, CH, CH, 2);
}

// Round 7
// 1559.374 us; speedup vs baseline: 2.6414x; 1.2639x over previous
//
#include <hip/hip_runtime.h>
#include <hip/hip_bf16.h>
#include <math.h>

// Problem constants (B=8, H=W=128, C=512, HEADS=8 -> kt=64 via _k_tokens)
#define NB     8
#define NSEQ   16384
#define NTOK   (NB*NSEQ)      // 131072
#define CH     512
#define CRD    256
#define NHEAD  8
#define DH     64
#define DHQ    32
#define KT     64
#define HH     128
#define WW     128
#define SCALEQ 0.17677669529663687f   // (64*0.5)^-0.5

typedef __attribute__((ext_vector_type(8))) short bf8_t;   // 8 bf16 (4 VGPR) MFMA operand
typedef __attribute__((ext_vector_type(4))) float f32x4;   // MFMA accumulator

// ---------------- wave helpers (wave = 64 lanes) ----------------
__device__ __forceinline__ float wsum(float v){
#pragma unroll
  for (int o=32;o;o>>=1) v += __shfl_xor(v,o,64);
  return v;
}

__device__ __forceinline__ unsigned short bf_bits(float f){
  __hip_bfloat16 h = __float2bfloat16(f);      // RNE
  return __builtin_bit_cast(unsigned short, h);
}
__device__ __forceinline__ float bf_back(unsigned short s){
  return __uint_as_float(((unsigned)s) << 16);
}

// ---------------- taps: T9[token][j] = sum_c x[token,c]*curv_w[c,j] ----------------
__global__ __launch_bounds__(256) void taps_kernel(const float* __restrict__ x,
    const float* __restrict__ curv_w, float* __restrict__ T9)
{
  __shared__ float ws_[CH*9];   // 18 KB
  int tid = threadIdx.x;
  for (int i=tid;i<CH*9;i+=256) ws_[i] = curv_w[i];
  __syncthreads();
  int wid = tid>>6, lane = tid&63;
  size_t token = (size_t)blockIdx.x*4 + wid;
  float acc[9] = {0,0,0,0,0,0,0,0,0};
#pragma unroll
  for (int i=0;i<8;++i){
    int c = lane + i*64;
    float xk = x[token*CH + c];
    const float* wp = &ws_[c*9];
#pragma unroll
    for (int j=0;j<9;++j) acc[j] += xk*wp[j];
  }
#pragma unroll
  for (int j=0;j<9;++j) acc[j] = wsum(acc[j]);
  if (lane==0){
#pragma unroll
    for (int j=0;j<9;++j) T9[token*9+j] = acc[j];
  }
}

// ---------------- split-bf16 MFMA GEMM: C[M,N] = A[M,K] @ W[N,K]^T (+bias) ----------------
// 3-term split: A=Ah+Al, W=Wh+Wl; C ~= Ah*Wh + Ah*Wl + Al*Wh (fp32-class accuracy).
#define LSTR 48
__global__ __launch_bounds__(256) void gemm3bf(
    const float* __restrict__ A, const float* __restrict__ Wm,
    const float* __restrict__ bias, float* __restrict__ C,
    int N, int K, int nbx_shift)
{
  __shared__ unsigned short Ah[128*LSTR], Al[128*LSTR], Bh[128*LSTR], Bl[128*LSTR]; // 48 KB
  const int tid = threadIdx.x;
  const int bid = blockIdx.x;
  const int nbx_mask = (1<<nbx_shift) - 1;
  const int bm = (bid >> nbx_shift) * 128;   // n fastest: adjacent blocks share A panel in L2
  const int bn = (bid & nbx_mask) * 128;

  const int w    = tid >> 6;        // wave 0..3
  const int lane = tid & 63;
  const int wr   = (w >> 1) * 64;   // wave row offset in tile
  const int wc   = (w & 1) * 64;    // wave col offset
  const int fr   = lane & 15;       // fragment row/col
  const int fs   = lane >> 4;       // fragment k-slot (0..3)

  f32x4 acc[4][4];
#pragma unroll
  for (int mt=0; mt<4; ++mt)
#pragma unroll
    for (int nt=0; nt<4; ++nt) acc[mt][nt] = (f32x4){0.f,0.f,0.f,0.f};

  float4 ra[4], rb[4];
#pragma unroll
  for (int i=0;i<4;++i){
    int c = i*256 + tid; int row = c>>3, ks = c&7;
    ra[i] = *(const float4*)(A  + (size_t)(bm+row)*K + ks*4);
    rb[i] = *(const float4*)(Wm + (size_t)(bn+row)*K + ks*4);
  }

  for (int k0=0; k0<K; k0+=32){
    __syncthreads();
#pragma unroll
    for (int i=0;i<4;++i){
      int c = i*256 + tid; int row = c>>3, ks = c&7;
      float4 va = ra[i], vb = rb[i];
      ushort4 ah4, al4, bh4, bl4;
      ah4.x = bf_bits(va.x); al4.x = bf_bits(va.x - bf_back(ah4.x));
      ah4.y = bf_bits(va.y); al4.y = bf_bits(va.y - bf_back(ah4.y));
      ah4.z = bf_bits(va.z); al4.z = bf_bits(va.z - bf_back(ah4.z));
      ah4.w = bf_bits(va.w); al4.w = bf_bits(va.w - bf_back(ah4.w));
      bh4.x = bf_bits(vb.x); bl4.x = bf_bits(vb.x - bf_back(bh4.x));
      bh4.y = bf_bits(vb.y); bl4.y = bf_bits(vb.y - bf_back(bh4.y));
      bh4.z = bf_bits(vb.z); bl4.z = bf_bits(vb.z - bf_back(bh4.z));
      bh4.w = bf_bits(vb.w); bl4.w = bf_bits(vb.w - bf_back(bh4.w));
      *(ushort4*)&Ah[row*LSTR + ks*4] = ah4;
      *(ushort4*)&Al[row*LSTR + ks*4] = al4;
      *(ushort4*)&Bh[row*LSTR + ks*4] = bh4;
      *(ushort4*)&Bl[row*LSTR + ks*4] = bl4;
    }
    __syncthreads();
    if (k0 + 32 < K){
#pragma unroll
      for (int i=0;i<4;++i){
        int c = i*256 + tid; int row = c>>3, ks = c&7;
        ra[i] = *(const float4*)(A  + (size_t)(bm+row)*K + k0+32 + ks*4);
        rb[i] = *(const float4*)(Wm + (size_t)(bn+row)*K + k0+32 + ks*4);
      }
    }
    bf8_t ahf[4], alf[4];
#pragma unroll
    for (int mt=0; mt<4; ++mt){
      int r = wr + mt*16 + fr;
      ahf[mt] = *(const bf8_t*)&Ah[r*LSTR + fs*8];
      alf[mt] = *(const bf8_t*)&Al[r*LSTR + fs*8];
    }
#pragma unroll
    for (int nt=0; nt<4; ++nt){
      int cix = wc + nt*16 + fr;
      bf8_t bhf = *(const bf8_t*)&Bh[cix*LSTR + fs*8];
      bf8_t blf = *(const bf8_t*)&Bl[cix*LSTR + fs*8];
#pragma unroll
      for (int mt=0; mt<4; ++mt){
        acc[mt][nt] = __builtin_amdgcn_mfma_f32_16x16x32_bf16(ahf[mt], bhf, acc[mt][nt], 0,0,0);
        acc[mt][nt] = __builtin_amdgcn_mfma_f32_16x16x32_bf16(ahf[mt], blf, acc[mt][nt], 0,0,0);
        acc[mt][nt] = __builtin_amdgcn_mfma_f32_16x16x32_bf16(alf[mt], bhf, acc[mt][nt], 0,0,0);
      }
    }
  }
#pragma unroll
  for (int nt=0; nt<4; ++nt){
    int col = bn + wc + nt*16 + fr;
    float bv = bias ? bias[col] : 0.f;
#pragma unroll
    for (int mt=0; mt<4; ++mt){
      int row0 = bm + wr + mt*16 + fs*4;
#pragma unroll
      for (int j=0;j<4;++j){
        C[(size_t)(row0+j)*N + col] = acc[mt][nt][j] + bv;
      }
    }
  }
}

// ---------------- 9-tap spatial combine -> curv_raw (pre-LN) ----------------
__global__ __launch_bounds__(256) void curv_combine(const float* __restrict__ T9,
    float* __restrict__ curv_raw)
{
  int gid = blockIdx.x*256 + threadIdx.x;
  int b = gid >> 14;
  int p = gid & (NSEQ-1);
  int i = p >> 7;
  int k = p & (WW-1);
  float s = 0.f;
#pragma unroll
  for (int dy=-1;dy<=1;++dy){
    int ii = i+dy;
    if (ii<0||ii>=HH) continue;
#pragma unroll
    for (int dx=-1;dx<=1;++dx){
      int kk = k+dx;
      if (kk<0||kk>=WW) continue;
      int j = (dy+1)*3 + (dx+1);
      s += T9[((size_t)b*NSEQ + ii*WW + kk)*9 + j];
    }
  }
  curv_raw[gid] = s * (1.0f/512.0f);
}

// ---------------- per-batch LN stats over N=16384 ----------------
__global__ __launch_bounds__(256) void stats_kernel(const float* __restrict__ curv_raw,
    float* __restrict__ stats)
{
  __shared__ float red[256];
  int b = blockIdx.x, tid = threadIdx.x;
  const float* cr = curv_raw + (size_t)b*NSEQ;
  float s=0.f;
  for (int i=tid;i<NSEQ;i+=256) s += cr[i];
  red[tid]=s; __syncthreads();
  for (int st=128;st;st>>=1){ if(tid<st) red[tid]+=red[tid+st]; __syncthreads(); }
  float mean = red[0] * (1.0f/NSEQ);
  __syncthreads();
  float vs=0.f;
  for (int i=tid;i<NSEQ;i+=256){ float d=cr[i]-mean; vs += d*d; }
  red[tid]=vs; __syncthreads();
  for (int st=128;st;st>>=1){ if(tid<st) red[tid]+=red[tid+st]; __syncthreads(); }
  if (tid==0){ stats[2*b]=mean; stats[2*b+1]=rsqrtf(red[0]*(1.0f/NSEQ) + 1e-5f); }
}

// ---------------- gate layer-2 + sigmoid + normalized curv + score ----------------
__global__ __launch_bounds__(256) void score_kernel(const float* __restrict__ h_pre,
    const float* __restrict__ w2, const float* __restrict__ b2,
    const float* __restrict__ curv_raw, const float* __restrict__ stats,
    float* __restrict__ score, float* __restrict__ curv_norm)
{
  int tid=threadIdx.x; int wid=tid>>6, lane=tid&63;
  size_t token = (size_t)blockIdx.x*4 + wid;
  int b = (int)(token >> 14);
  const float* h = h_pre + token*CRD;
  float acc=0.f;
#pragma unroll
  for (int i=0;i<4;++i){
    int c = lane + i*64;
    float hv = fmaxf(h[c], 0.f);
    acc += hv * w2[c];
  }
  acc = wsum(acc);
  if (lane==0){
    float z = acc + b2[0];
    float gate = 1.0f/(1.0f + expf(-z));
    float cn = (curv_raw[token] - stats[2*b]) * stats[2*b+1];
    curv_norm[token] = cn;
    score[token] = 0.5f*(fabsf(cn) + gate);   // score > 0 always (|.| + sigmoid)
  }
}

// ---------------- exact top-64 via two-stage bitonic sort on packed keys ----------------
__device__ __forceinline__ void bitonic_sort_desc_1024(unsigned long long* keys, int tid){
  for (int k=2;k<=1024;k<<=1){
    for (int j=k>>1;j>0;j>>=1){
#pragma unroll
      for (int r=0;r<2;++r){
        int t = tid + r*512;
        int ixj = t ^ j;
        if (ixj > t){
          bool desc = ((t & k) == 0);
          unsigned long long a = keys[t], b = keys[ixj];
          bool sw = desc ? (a < b) : (a > b);
          if (sw){ keys[t]=b; keys[ixj]=a; }
        }
      }
      __syncthreads();
    }
  }
}

__global__ __launch_bounds__(512) void topk_stage1(const float* __restrict__ score,
    unsigned long long* __restrict__ cand)
{
  __shared__ unsigned long long keys[1024];   // 8 KB
  int blk = blockIdx.x;           // b*16 + chunk
  int b = blk >> 4, chunk = blk & 15;
  int tid = threadIdx.x;
  const float* sc = score + (size_t)b*NSEQ + chunk*1024;
#pragma unroll
  for (int r=0;r<2;++r){
    int t = tid + r*512;
    unsigned int vb = __float_as_uint(sc[t]);
    unsigned int gi = (unsigned)(chunk*1024 + t);
    keys[t] = ((unsigned long long)vb << 32) | (unsigned long long)(0xFFFFFFFFu - gi);
  }
  __syncthreads();
  bitonic_sort_desc_1024(keys, tid);
  if (tid < KT) cand[(size_t)blk*KT + tid] = keys[tid];
}

__global__ __launch_bounds__(512) void topk_stage2(const unsigned long long* __restrict__ cand,
    int* __restrict__ idx_out, float* __restrict__ val_out)
{
  __shared__ unsigned long long keys[1024];   // 16 chunks x 64 candidates
  int b = blockIdx.x; int tid = threadIdx.x;
  keys[tid]     = cand[(size_t)b*1024 + tid];
  keys[tid+512] = cand[(size_t)b*1024 + tid + 512];
  __syncthreads();
  bitonic_sort_desc_1024(keys, tid);
  if (tid < KT){
    unsigned long long kk = keys[tid];
    val_out[b*KT+tid] = __uint_as_float((unsigned)(kk >> 32));
    idx_out[b*KT+tid] = (int)(0xFFFFFFFFu - (unsigned)(kk & 0xFFFFFFFFu));
  }
}

// ---------------- kv = gelu(LN(x_topk @ kvr_w^T + kvr_b)); also gather curv_topk ----------------
__global__ __launch_bounds__(256) void kva_kernel(const float* __restrict__ x,
    const int* __restrict__ topk_idx, const float* __restrict__ kvr_w,
    const float* __restrict__ kvr_b, const float* __restrict__ ln_g,
    const float* __restrict__ ln_b, const float* __restrict__ curv_norm,
    float* __restrict__ kv, float* __restrict__ curv_top)
{
  __shared__ float xs[CH];
  __shared__ float red[CRD];
  int blk=blockIdx.x; int b=blk>>6, t=blk&63; int tid=threadIdx.x;
  int row = topk_idx[b*KT+t];
  const float* xr = x + ((size_t)b*NSEQ + row)*CH;
  xs[tid]=xr[tid]; xs[tid+256]=xr[tid+256];
  __syncthreads();
  float acc = kvr_b[tid];
  const float4* wr = (const float4*)(kvr_w + (size_t)tid*CH);
  const float4* x4 = (const float4*)xs;
#pragma unroll 8
  for (int i=0;i<CH/4;++i){
    float4 w4=wr[i]; float4 xv=x4[i];
    acc += w4.x*xv.x + w4.y*xv.y + w4.z*xv.z + w4.w*xv.w;
  }
  red[tid]=acc; __syncthreads();
  for (int st=128;st;st>>=1){ if(tid<st) red[tid]+=red[tid+st]; __syncthreads(); }
  float mean = red[0]*(1.0f/CRD);
  __syncthreads();
  float d = acc-mean;
  red[tid]=d*d; __syncthreads();
  for (int st=128;st;st>>=1){ if(tid<st) red[tid]+=red[tid+st]; __syncthreads(); }
  float rstd = rsqrtf(red[0]*(1.0f/CRD) + 1e-5f);
  float y = (acc-mean)*rstd*ln_g[tid] + ln_b[tid];
  float ge = 0.5f*y*(1.0f + erff(y*0.70710678118654752f));   // exact gelu
  kv[((size_t)b*KT+t)*CRD + tid] = ge;
  if (tid==0) curv_top[b*KT+t] = curv_norm[(size_t)b*NSEQ + row];
}

// ---------------- kmat = kv@k_w^T ; v = (kv@v_w^T) * score_topk ----------------
__global__ __launch_bounds__(256) void kvb_kernel(const float* __restrict__ kv,
    const float* __restrict__ k_w, const float* __restrict__ v_w,
    const float* __restrict__ topk_val, float* __restrict__ kmat,
    float* __restrict__ vbuf)
{
  __shared__ float ks[CRD];
  int blk=blockIdx.x; int b=blk>>6, t=blk&63; int tid=threadIdx.x;
  ks[tid] = kv[((size_t)b*KT+t)*CRD + tid];
  __syncthreads();
  float sv = topk_val[b*KT+t];
  const float4* k4 = (const float4*)ks;
  const float4* wk = (const float4*)(k_w + (size_t)tid*CRD);
  float a=0.f;
#pragma unroll 8
  for (int i=0;i<CRD/4;++i){ float4 w4=wk[i]; float4 xv=k4[i]; a += w4.x*xv.x+w4.y*xv.y+w4.z*xv.z+w4.w*xv.w; }
  kmat[((size_t)b*KT+t)*CRD + tid] = a;
  const float4* wv0 = (const float4*)(v_w + (size_t)tid*CRD);
  const float4* wv1 = (const float4*)(v_w + (size_t)(tid+256)*CRD);
  float v0=0.f, v1=0.f;
#pragma unroll 8
  for (int i=0;i<CRD/4;++i){
    float4 xv=k4[i];
    float4 wa=wv0[i]; v0 += wa.x*xv.x+wa.y*xv.y+wa.z*xv.z+wa.w*xv.w;
    float4 wb=wv1[i]; v1 += wb.x*xv.x+wb.y*xv.y+wb.z*xv.z+wb.w*xv.w;
  }
  vbuf[((size_t)b*KT+t)*CH + tid]       = v0*sv;
  vbuf[((size_t)b*KT+t)*CH + 256 + tid] = v1*sv;
}

// ---------------- CPE: depthwise 3x3 over the 8x8 topk grid, v2 = v + cpe ----------------
// One thread per (b,t,ch) output element: 1024 blocks x 256 threads, fully parallel.
// (Was 8 blocks with a 64-iteration serial loop -> launch-width/latency-bound.)
__global__ __launch_bounds__(256) void cpe_kernel(const float* __restrict__ vbuf,
    const float* __restrict__ cpe_w, const float* __restrict__ cpe_b,
    float* __restrict__ v2)
{
  int gid = blockIdx.x*256 + threadIdx.x;   // NB*KT*CH = 262144
  int ch = gid & (CH-1);
  int t  = (gid >> 9) & (KT-1);
  int b  = gid >> 15;
  int gi = t>>3, gj = t&7;
  const float* vb = vbuf + (size_t)b*KT*CH;
  float s = cpe_b[ch];
#pragma unroll
  for (int dy=-1;dy<=1;++dy){
    int ii=gi+dy; if (ii<0||ii>=8) continue;
#pragma unroll
    for (int dx=-1;dx<=1;++dx){
      int jj=gj+dx; if (jj<0||jj>=8) continue;
      s += cpe_w[ch*9 + (dy+1)*3+(dx+1)] * vb[(ii*8+jj)*CH + ch];
    }
  }
  v2[(size_t)b*KT*CH + t*CH + ch] = vb[t*CH + ch] + s;
}

// ---------------- attention: thread-per-query, dual softmax over kt=64 keys ----------------
// 256 threads = 256 queries/block. K[64][32]+V[64][64] in LDS (24.25 KB); all lanes
// read the same LDS word in lockstep -> broadcast, conflict-free, zero cross-lane ops.
// 3 passes over keys (max / sums / weighted-PV); dots recomputed (32 FMA, cheaper
// than storing 64 logits in VGPR/LDS).
__global__ __launch_bounds__(256) void attn_kernel(const float* __restrict__ Q,
    const float* __restrict__ kmat, const float* __restrict__ v2,
    const float* __restrict__ curv_top, const float* __restrict__ alpha_p,
    const float* __restrict__ beta_p, float* __restrict__ out)
{
  __shared__ float Ks[KT][DHQ];    // 8 KB
  __shared__ float Vs[KT][DH];     // 16 KB
  __shared__ float fm[KT];
  int bid = blockIdx.x;
  int chunk = bid & 63;
  int hh = (bid>>6) & 7;
  int b = bid>>9;
  int tid = threadIdx.x;
  float alpha = alpha_p[0], beta = beta_p[0];
  for (int i=tid;i<KT*DHQ/4;i+=256){
    int t = i >> 3, d4 = i & 7;
    *(float4*)&Ks[t][d4*4] = *(const float4*)&kmat[((size_t)b*KT+t)*CRD + hh*DHQ + d4*4];
  }
  for (int i=tid;i<KT*DH/4;i+=256){
    int t = i >> 4, d4 = i & 15;
    *(float4*)&Vs[t][d4*4] = *(const float4*)&v2[((size_t)b*KT+t)*CH + hh*DH + d4*4];
  }
  if (tid<KT) fm[tid] = 1.0f + alpha*curv_top[b*KT+tid];
  __syncthreads();

  int n = chunk*256 + tid;
  const float* qp = Q + ((size_t)b*NSEQ + n)*CRD + hh*DHQ;
  float q[DHQ];
#pragma unroll
  for (int i=0;i<8;++i) *(float4*)&q[i*4] = *(const float4*)&qp[i*4];

  // pass 1: maxes of both logit streams
  float m1=-1e30f, m2=-1e30f;
  for (int k=0;k<KT;++k){
    float lg=0.f;
#pragma unroll
    for (int d=0;d<DHQ;++d) lg = fmaf(q[d], Ks[k][d], lg);
    lg *= SCALEQ;
    m1 = fmaxf(m1, lg);
    m2 = fmaxf(m2, lg*fm[k]);
  }
  // pass 2: denominators
  float s1=0.f, s2=0.f;
  for (int k=0;k<KT;++k){
    float lg=0.f;
#pragma unroll
    for (int d=0;d<DHQ;++d) lg = fmaf(q[d], Ks[k][d], lg);
    lg *= SCALEQ;
    s1 += __expf(lg - m1);
    s2 += __expf(lg*fm[k] - m2);
  }
  float r1 = beta/s1, r2 = (1.0f-beta)/s2;
  // pass 3: weighted V accumulation
  float acc[DH];
#pragma unroll
  for (int d=0;d<DH;++d) acc[d]=0.f;
  for (int k=0;k<KT;++k){
    float lg=0.f;
#pragma unroll
    for (int d=0;d<DHQ;++d) lg = fmaf(q[d], Ks[k][d], lg);
    lg *= SCALEQ;
    float at = r1*__expf(lg - m1) + r2*__expf(lg*fm[k] - m2);
#pragma unroll
    for (int d=0;d<DH;++d) acc[d] = fmaf(at, Vs[k][d], acc[d]);
  }
  float* op = out + ((size_t)b*NSEQ+n)*CH + hh*DH;
#pragma unroll
  for (int i=0;i<16;++i) *(float4*)&op[i*4] = *(float4*)&acc[i*4];
}

// ---------------- launch ----------------
extern "C" void kernel_launch(void* const* d_in, const int* in_sizes, int n_in,
                              void* d_out, int out_size, void* d_ws, size_t ws_size,
                              hipStream_t stream)
{
  (void)in_sizes; (void)n_in; (void)out_size; (void)ws_size;
  const float* x      = (const float*)d_in[0];
  const float* curv_w = (const float*)d_in[1];
  const float* gate_w1= (const float*)d_in[2];
  const float* gate_b1= (const float*)d_in[3];
  const float* gate_w2= (const float*)d_in[4];
  const float* gate_b2= (const float*)d_in[5];
  const float* q_w    = (const float*)d_in[6];
  const float* kvr_w  = (const float*)d_in[7];
  const float* kvr_b  = (const float*)d_in[8];
  const float* ln_g   = (const float*)d_in[9];
  const float* ln_b   = (const float*)d_in[10];
  const float* k_w    = (const float*)d_in[11];
  const float* v_w    = (const float*)d_in[12];
  const float* cpe_w  = (const float*)d_in[13];
  const float* cpe_b  = (const float*)d_in[14];
  const float* proj_w = (const float*)d_in[15];
  const float* proj_b = (const float*)d_in[16];
  const float* alpha  = (const float*)d_in[17];
  const float* beta   = (const float*)d_in[18];

  // workspace layout (bytes). Region A first holds {h_pre, T9, curv_raw, score}
  // (dead after topk/score), then is reused as attn_out. cand aliases dead T9.
  char* ws = (char*)d_ws;
  float* attn_out = (float*)(ws);
  float* h_pre    = (float*)(ws);                        // NTOK*256 f32 = 134217728 B
  float* T9       = (float*)(ws + 134217728);            // NTOK*9 f32   = 4718592 B
  unsigned long long* cand = (unsigned long long*)(ws + 134217728);  // 64 KB (aliases dead T9)
  float* curv_raw = (float*)(ws + 138936320);            // NTOK f32
  float* score    = (float*)(ws + 139460608);            // NTOK f32
  float* Qbuf     = (float*)(ws + 268435456);            // NTOK*256 f32
  char*  c0       = ws + 402653184;                      // small-buffer region
  float* curv_norm= (float*)(c0 + 0);
  float* stats    = (float*)(c0 + 524288);
  int*   topk_idx = (int*)  (c0 + 524544);
  float* topk_val = (float*)(c0 + 526592);
  float* curv_top = (float*)(c0 + 528640);
  float* kvbuf    = (float*)(c0 + 530688);
  float* kmat     = (float*)(c0 + 1054976);
  float* vbuf     = (float*)(c0 + 1579264);
  float* v2buf    = (float*)(c0 + 2627840);
  float* outp     = (float*)d_out;

  taps_kernel <<<NTOK/4, 256, 0, stream>>>(x, curv_w, T9);
  gemm3bf     <<<(NTOK/128)*2, 256, 0, stream>>>(x, gate_w1, gate_b1, h_pre, CRD, CH, 1);
  gemm3bf     <<<(NTOK/128)*2, 256, 0, stream>>>(x, q_w, nullptr, Qbuf, CRD, CH, 1);
  curv_combine<<<NTOK/256, 256, 0, stream>>>(T9, curv_raw);
  stats_kernel<<<NB, 256, 0, stream>>>(curv_raw, stats);
  score_kernel<<<NTOK/4, 256, 0, stream>>>(h_pre, gate_w2, gate_b2, curv_raw, stats, score, curv_norm);
  topk_stage1 <<<NB*16, 512, 0, stream>>>(score, cand);
  topk_stage2 <<<NB, 512, 0, stream>>>(cand, topk_idx, topk_val);
  kva_kernel  <<<NB*KT, 256, 0, stream>>>(x, topk_idx, kvr_w, kvr_b, ln_g, ln_b, curv_norm, kvbuf, curv_top);
  kvb_kernel  <<<NB*KT, 256, 0, stream>>>(kvbuf, k_w, v_w, topk_val, kmat, vbuf);
  cpe_kernel  <<<NB*KT*CH/256, 256, 0, stream>>>(vbuf, cpe_w, cpe_b, v2buf);
  attn_kernel <<<NB*NHEAD*(NSEQ/256), 256, 0, stream>>>(Qbuf, kmat, v2buf, curv_top, alpha, beta, attn_out);
  gemm3bf     <<<(NTOK/128)*4, 256, 0, stream>>>(attn_out, proj_w, proj_b, outp, CH, CH, 2);
}